// Round 8
// baseline (1469.213 us; speedup 1.0000x reference)
//
#include <hip/hip_runtime.h>

#define B_ 16
#define N_ 4096
#define S_ 1024
#define K_ 32
#define PITCH2 136   // 128 + 8 shorts: b128 frag reads -> 2-way bank alias (free)
#define PITCH1 168   // 160 + 8 shorts
#define OPITCH 136   // output-tile pitch for epilogue transpose

typedef unsigned long long u64;
typedef short bf16x8 __attribute__((ext_vector_type(8)));
typedef float f32x4 __attribute__((ext_vector_type(4)));
typedef float f32x2 __attribute__((ext_vector_type(2)));

__device__ __forceinline__ unsigned short f2bf(float f) {
  unsigned u = __float_as_uint(f);
  unsigned r = (u + 0x7FFFu + ((u >> 16) & 1u)) >> 16;
  return (unsigned short)r;
}
__device__ __forceinline__ float bf2f(unsigned short h) {
  return __uint_as_float(((unsigned)h) << 16);
}

// DPP wave64 max reduce: shr1,2,4,8 + bcast15 + bcast31 -> lane 63 = wave max
#define DPP_MAX(v, ctrl)                                                        \
  {                                                                             \
    int _t = __builtin_amdgcn_update_dpp(__float_as_int(v), __float_as_int(v),  \
                                         ctrl, 0xf, 0xf, false);                \
    v = fmaxf(v, __int_as_float(_t));                                           \
  }

// ===== fused front kernel: blocks 0-15 FPS | 16-31 init | 32+ transpose =====
__global__ __launch_bounds__(512) void k_front(
    const float* __restrict__ xyz, float* __restrict__ new_xyz,
    const float* __restrict__ feat, unsigned short* __restrict__ featT,
    const float* __restrict__ w0, const float* __restrict__ w1,
    const float* __restrict__ w2, unsigned short* __restrict__ wbf0,
    unsigned short* __restrict__ wbf1, unsigned short* __restrict__ wbf2,
    float* __restrict__ stats) {
  __shared__ __align__(16) float smem[N_ * 4 + S_ + 64];  // 64KB pts + 4KB idxs + keys
  int blk = blockIdx.x, t = threadIdx.x;

  if (blk < 16) {
#pragma clang fp contract(off)
    // ---------------- farthest point sampling ----------------
    // 512 thr, 8 pts/thread. Distance math bit-exact vs numpy
    // (((dx*dx+dy*dy)+dz*dz), rn, no contraction). One barrier/iter,
    // no global memory inside the loop.
#if __has_builtin(__builtin_amdgcn_s_setprio)
    __builtin_amdgcn_s_setprio(3);
#endif
    float4* pts = (float4*)smem;              // [4096]
    int* idxs = (int*)(smem + N_ * 4);        // [1024]
    u64* swk = (u64*)(smem + N_ * 4 + S_);    // [2][8]
    int b = blk;
    const float* base = xyz + (size_t)b * N_ * 3;
    for (int i = t; i < N_; i += 512)
      pts[i] = make_float4(base[i * 3], base[i * 3 + 1], base[i * 3 + 2], 0.0f);
    if (t == 0) idxs[0] = 0;
    __syncthreads();
    f32x2 px[4], py[4], pz[4], pd[4];
    int i0 = t * 8;
    #pragma unroll
    for (int j = 0; j < 4; ++j) {
      float4 p0 = pts[i0 + 2 * j], p1 = pts[i0 + 2 * j + 1];
      px[j] = (f32x2){p0.x, p1.x};
      py[j] = (f32x2){p0.y, p1.y};
      pz[j] = (f32x2){p0.z, p1.z};
      pd[j] = (f32x2){1e10f, 1e10f};
    }
    int cur = 0;
    for (int it = 0; it < S_; ++it) {
      float4 c = pts[cur];
      f32x2 c2x = (f32x2){c.x, c.x}, c2y = (f32x2){c.y, c.y}, c2z = (f32x2){c.z, c.z};
      float bestv = -1.0f; int besti = 0;
      #pragma unroll
      for (int j = 0; j < 4; ++j) {
        f32x2 dx = px[j] - c2x;
        f32x2 dy = py[j] - c2y;
        f32x2 dz = pz[j] - c2z;
        f32x2 d = (dx * dx + dy * dy) + dz * dz;
        f32x2 dm = __builtin_elementwise_min(pd[j], d);
        pd[j] = dm;
        if (dm.x > bestv) { bestv = dm.x; besti = 2 * j; }
        if (dm.y > bestv) { bestv = dm.y; besti = 2 * j + 1; }
      }
      float v = bestv;
      DPP_MAX(v, 0x111);
      DPP_MAX(v, 0x112);
      DPP_MAX(v, 0x114);
      DPP_MAX(v, 0x118);
      DPP_MAX(v, 0x142);
      DPP_MAX(v, 0x143);
      float wmax = __int_as_float(__builtin_amdgcn_readlane(__float_as_int(v), 63));
      u64 mask = __ballot(bestv == wmax);
      int owner = __ffsll((long long)mask) - 1;
      int widx = __builtin_amdgcn_readlane(i0 + besti, owner);
      if ((t & 63) == 0)
        swk[(it & 1) * 8 + (t >> 6)] =
            ((u64)__float_as_uint(wmax) << 32) | (unsigned)(4095 - widx);
      __syncthreads();
      const u64* kk = swk + (it & 1) * 8;
      u64 k0 = kk[0];
      #pragma unroll
      for (int w = 1; w < 8; ++w) if (kk[w] > k0) k0 = kk[w];
      cur = 4095 - (int)(unsigned)(k0 & 0xFFFFFFFFull);
      if (t == 0 && it + 1 < S_) idxs[it + 1] = cur;
    }
    __syncthreads();
    for (int i = t; i < S_; i += 512) {
      float4 v = pts[idxs[i]];
      size_t o = ((size_t)b * S_ + i) * 3;
      new_xyz[o] = v.x; new_xyz[o + 1] = v.y; new_xyz[o + 2] = v.z;
    }
  } else if (blk < 32) {
    // ---------------- init: zero stats, weights -> bf16 [n][k] ----------------
    int id = (blk - 16) * 512 + t;
    const int st = 16 * 512;
    for (int i = id; i < 32768; i += st) stats[i] = 0.0f;
    for (int i = id; i < 128 * 160; i += st) {
      int n = i / 160, k = i - n * 160;
      float v = (k < 128) ? w0[n * 131 + 3 + k] : (k < 131) ? w0[n * 131 + k - 128] : 0.0f;
      wbf0[i] = f2bf(v);
    }
    for (int i = id; i < 128 * 128; i += st) wbf1[i] = f2bf(w1[i]);
    for (int i = id; i < 256 * 128; i += st) wbf2[i] = f2bf(w2[i]);
  } else {
    // ------------- transpose features (B,C,N) f32 -> (B,N,C) bf16 -------------
    float (*tile)[33] = (float(*)[33])smem;
    int blk2 = blk - 32;
    int n0 = (blk2 & 127) * 32;
    int c0 = ((blk2 >> 7) & 3) * 32;
    int b = blk2 >> 9;
    int tx = t & 31, ty = t >> 5;
    #pragma unroll
    for (int j = 0; j < 32; j += 16)
      tile[ty + j][tx] = feat[((size_t)b * 128 + c0 + ty + j) * N_ + n0 + tx];
    __syncthreads();
    #pragma unroll
    for (int j = 0; j < 32; j += 16)
      featT[((size_t)b * N_ + n0 + ty + j) * 128 + c0 + tx] = f2bf(tile[tx][ty + j]);
  }
}

// ============ MFMA layer kernels ============
#define MFMA(a, b, c) __builtin_amdgcn_mfma_f32_16x16x32_bf16(a, b, c, 0, 0, 0)

// ---- layer 1: fused ballq + gather + matmul K=131(pad160)->128 ----
// Per block: 4 queries (one per wave). Wave computes its query's ball list
// (bit-exact reference formula) into LDS, then the usual staged MFMA.
// Epilogue: LDS transpose -> fully coalesced uint4 y stores (r8 fix).
__global__ __launch_bounds__(256) void k_layer1(
    const float* __restrict__ xyz, const float* __restrict__ new_xyz,
    const unsigned short* __restrict__ featT,
    const unsigned short* __restrict__ wbf0, const float* __restrict__ b0,
    unsigned short* __restrict__ y, float* __restrict__ stats) {
  __shared__ __align__(16) unsigned short Wl[128 * PITCH1];
  __shared__ __align__(16) unsigned short Gl[128 * PITCH1];
  __shared__ float sbias[128];
  __shared__ int sball[4 * K_];
  int bb = blockIdx.y, s0 = blockIdx.x * 4, t = threadIdx.x;
  int w = t >> 6, L = t & 63;

  // ---- ball query: wave w -> query s0+w (bit-exact formula) ----
  {
    const float* pb = xyz + (size_t)bb * N_ * 3;
    size_t q = (size_t)bb * S_ + s0 + w;
    float qx = new_xyz[q * 3], qy = new_xyz[q * 3 + 1], qz = new_xyz[q * 3 + 2];
    float sq = __fadd_rn(__fadd_rn(__fmul_rn(qx, qx), __fmul_rn(qy, qy)), __fmul_rn(qz, qz));
    int* out = sball + w * K_;
    int total = 0;
    int first_idx = -1;
    for (int basei = 0; basei < N_; basei += 64) {
      int i = basei + L;
      float fx = pb[i * 3], fy = pb[i * 3 + 1], fz = pb[i * 3 + 2];
      float dot = __fmul_rn(qx, fx);
      dot = __fadd_rn(dot, __fmul_rn(qy, fy));
      dot = __fadd_rn(dot, __fmul_rn(qz, fz));
      float sd = __fadd_rn(__fadd_rn(__fmul_rn(fx, fx), __fmul_rn(fy, fy)), __fmul_rn(fz, fz));
      float dist = __fadd_rn(__fadd_rn(__fmul_rn(-2.0f, dot), sq), sd);
      bool within = (dist <= 0.36f);
      u64 m = __ballot(within);
      if (first_idx < 0 && m) first_idx = basei + __ffsll((long long)m) - 1;
      if (within) {
        int pos = total + __popcll(m & ((1ull << L) - 1ull));
        if (pos < K_) out[pos] = i;
      }
      total += (int)__popcll(m);
      if (total >= K_) break;
    }
    if (total < K_) {
      int k2 = total + L;
      if (k2 < K_) out[k2] = first_idx;
    }
  }
  // ---- stage W ----
  {
    int n = t >> 1, h = t & 1;
    const uint4* wr = (const uint4*)(wbf0 + n * 160 + h * 80);
    uint4* wl = (uint4*)(Wl + n * PITCH1 + h * 80);
    #pragma unroll
    for (int i = 0; i < 10; ++i) wl[i] = wr[i];
    if (t < 128) sbias[t] = b0[t];
  }
  // ---- gather G (ball indices from LDS, same-wave -> no barrier needed) ----
  {
    int r = t >> 1, h = t & 1;
    int ks = r & 31;
    size_t qg = (size_t)bb * S_ + s0 + (r >> 5);
    int p = sball[(r >> 5) * K_ + ks];
    const uint4* fr = (const uint4*)(featT + ((size_t)bb * N_ + p) * 128 + h * 64);
    uint4* gr = (uint4*)(Gl + r * PITCH1 + h * 64);
    #pragma unroll
    for (int i = 0; i < 8; ++i) gr[i] = fr[i];
    if (h == 0) {
      const float* pp = xyz + ((size_t)bb * N_ + p) * 3;
      Gl[r * PITCH1 + 128] = f2bf(pp[0] - new_xyz[qg * 3]);
      Gl[r * PITCH1 + 129] = f2bf(pp[1] - new_xyz[qg * 3 + 1]);
      Gl[r * PITCH1 + 130] = f2bf(pp[2] - new_xyz[qg * 3 + 2]);
    } else {
      for (int k = 131; k < 160; ++k) Gl[r * PITCH1 + k] = 0;
    }
  }
  __syncthreads();
  int lm = L & 15, lg = L >> 4;
  f32x4 acc[2][8];
  #pragma unroll
  for (int mi = 0; mi < 2; ++mi)
    #pragma unroll
    for (int nt = 0; nt < 8; ++nt) acc[mi][nt] = (f32x4){0.f, 0.f, 0.f, 0.f};
  for (int kt = 0; kt < 5; ++kt) {
    int ko = kt * 32 + lg * 8;
    bf16x8 a0 = *(const bf16x8*)&Gl[(w * 32 + lm) * PITCH1 + ko];
    bf16x8 a1 = *(const bf16x8*)&Gl[(w * 32 + 16 + lm) * PITCH1 + ko];
    bf16x8 bv[8];
    #pragma unroll
    for (int nt = 0; nt < 8; ++nt)
      bv[nt] = *(const bf16x8*)&Wl[(nt * 16 + lm) * PITCH1 + ko];
    #pragma unroll
    for (int nt = 0; nt < 8; ++nt) {
      acc[0][nt] = MFMA(a0, bv[nt], acc[0][nt]);
      acc[1][nt] = MFMA(a1, bv[nt], acc[1][nt]);
    }
  }
  // ---- epilogue: stats + LDS transpose (wave writes only its own rows) ----
  int slot = blockIdx.x & 31;
  #pragma unroll
  for (int nt = 0; nt < 8; ++nt) {
    int col = nt * 16 + lm;
    float bo = sbias[col];
    float s1 = 0.f, s2 = 0.f;
    #pragma unroll
    for (int mi = 0; mi < 2; ++mi)
      #pragma unroll
      for (int r = 0; r < 4; ++r) {
        float yv = acc[mi][nt][r] + bo;
        s1 += yv; s2 += yv * yv;
        int rr = w * 32 + mi * 16 + lg * 4 + r;
        Gl[rr * OPITCH + col] = f2bf(yv);
      }
    s1 += __shfl_xor(s1, 16); s2 += __shfl_xor(s2, 16);
    s1 += __shfl_xor(s1, 32); s2 += __shfl_xor(s2, 32);
    if (lg == 0) {
      atomicAdd(stats + ((size_t)slot * 128 + col) * 2, s1);
      atomicAdd(stats + ((size_t)slot * 128 + col) * 2 + 1, s2);
    }
  }
  __syncthreads();
  // ---- coalesced streaming store of the 128x128 tile ----
  {
    int rr = t >> 1, ch = (t & 1) * 64;
    const uint4* src = (const uint4*)&Gl[rr * OPITCH + ch];
    uint4* dst = (uint4*)(y + (((size_t)bb * S_ + s0) * K_ + rr) * 128 + ch);
    #pragma unroll
    for (int i = 0; i < 8; ++i) dst[i] = src[i];
  }
}

__global__ void k_finalize(const float* __restrict__ stats, const float* __restrict__ gamma,
                           const float* __restrict__ beta, float* __restrict__ murs, int C) {
  for (int c = threadIdx.x; c < C; c += blockDim.x) {
    float s1 = 0.0f, s2 = 0.0f;
    for (int sl = 0; sl < 32; ++sl) {
      s1 += stats[((size_t)sl * C + c) * 2];
      s2 += stats[((size_t)sl * C + c) * 2 + 1];
    }
    const float inv = 1.0f / 524288.0f;  // 2^-19, exact
    float mu = s1 * inv;
    float var = s2 * inv - mu * mu;
    float a = gamma[c] * rsqrtf(var + 1e-5f);
    murs[c * 2] = a;
    murs[c * 2 + 1] = beta[c] - a * mu;
  }
}

// ---- layer 2: BN+relu(y) -> matmul 128->128, y IN-PLACE, coalesced stores ----
__global__ __launch_bounds__(256) void k_layer2(
    unsigned short* y, const float* __restrict__ murs,
    const unsigned short* __restrict__ wbf1, const float* __restrict__ b1,
    float* __restrict__ stats) {
  __shared__ __align__(16) unsigned short Wl[128 * PITCH2];
  __shared__ __align__(16) unsigned short Gl[128 * PITCH2];
  __shared__ float sa[128], sd[128], sbias[128];
  int bb = blockIdx.y, s0 = blockIdx.x * 4, t = threadIdx.x;
  {
    int n = t >> 1, h = t & 1;
    const uint4* wr = (const uint4*)(wbf1 + n * 128 + h * 64);
    uint4* wl = (uint4*)(Wl + n * PITCH2 + h * 64);
    #pragma unroll
    for (int i = 0; i < 8; ++i) wl[i] = wr[i];
    if (t < 128) { sa[t] = murs[t * 2]; sd[t] = murs[t * 2 + 1]; sbias[t] = b1[t]; }
  }
  __syncthreads();
  {
    int r = t >> 1, h = t & 1;
    int q = r >> 5, ks = r & 31;
    size_t qg = (size_t)bb * S_ + s0 + q;
    const ushort4* yr = (const ushort4*)(y + (qg * K_ + ks) * 128 + h * 64);
    #pragma unroll
    for (int i = 0; i < 16; ++i) {
      ushort4 p = yr[i];
      int c = h * 64 + i * 4;
      ushort4 pk;
      pk.x = f2bf(fmaxf(sa[c]     * bf2f(p.x) + sd[c],     0.f));
      pk.y = f2bf(fmaxf(sa[c + 1] * bf2f(p.y) + sd[c + 1], 0.f));
      pk.z = f2bf(fmaxf(sa[c + 2] * bf2f(p.z) + sd[c + 2], 0.f));
      pk.w = f2bf(fmaxf(sa[c + 3] * bf2f(p.w) + sd[c + 3], 0.f));
      *(ushort4*)&Gl[r * PITCH2 + c] = pk;
    }
  }
  __syncthreads();
  int w = t >> 6, L = t & 63, lm = L & 15, lg = L >> 4;
  f32x4 acc[2][8];
  #pragma unroll
  for (int mi = 0; mi < 2; ++mi)
    #pragma unroll
    for (int nt = 0; nt < 8; ++nt) acc[mi][nt] = (f32x4){0.f, 0.f, 0.f, 0.f};
  for (int kt = 0; kt < 4; ++kt) {
    int ko = kt * 32 + lg * 8;
    bf16x8 a0 = *(const bf16x8*)&Gl[(w * 32 + lm) * PITCH2 + ko];
    bf16x8 a1 = *(const bf16x8*)&Gl[(w * 32 + 16 + lm) * PITCH2 + ko];
    bf16x8 bv[8];
    #pragma unroll
    for (int nt = 0; nt < 8; ++nt)
      bv[nt] = *(const bf16x8*)&Wl[(nt * 16 + lm) * PITCH2 + ko];
    #pragma unroll
    for (int nt = 0; nt < 8; ++nt) {
      acc[0][nt] = MFMA(a0, bv[nt], acc[0][nt]);
      acc[1][nt] = MFMA(a1, bv[nt], acc[1][nt]);
    }
  }
  // epilogue: stats + LDS transpose (wave overwrites its own rows; same pitch)
  int slot = blockIdx.x & 31;
  #pragma unroll
  for (int nt = 0; nt < 8; ++nt) {
    int col = nt * 16 + lm;
    float bo = sbias[col];
    float s1 = 0.f, s2 = 0.f;
    #pragma unroll
    for (int mi = 0; mi < 2; ++mi)
      #pragma unroll
      for (int r = 0; r < 4; ++r) {
        float yv = acc[mi][nt][r] + bo;
        s1 += yv; s2 += yv * yv;
        int rr = w * 32 + mi * 16 + lg * 4 + r;
        Gl[rr * OPITCH + col] = f2bf(yv);
      }
    s1 += __shfl_xor(s1, 16); s2 += __shfl_xor(s2, 16);
    s1 += __shfl_xor(s1, 32); s2 += __shfl_xor(s2, 32);
    if (lg == 0) {
      atomicAdd(stats + ((size_t)slot * 128 + col) * 2, s1);
      atomicAdd(stats + ((size_t)slot * 128 + col) * 2 + 1, s2);
    }
  }
  __syncthreads();
  {
    int rr = t >> 1, ch = (t & 1) * 64;
    const uint4* src = (const uint4*)&Gl[rr * OPITCH + ch];
    uint4* dst = (uint4*)(y + (((size_t)bb * S_ + s0) * K_ + rr) * 128 + ch);
    #pragma unroll
    for (int i = 0; i < 8; ++i) dst[i] = src[i];
  }
}

// ---- layer 3: BN+relu(y) -> matmul 128->256 (N split by blockIdx.z),
//      maxpool commutes with monotone BN+relu -> store ymax/ymin only ----
__global__ __launch_bounds__(256) void k_layer3(
    const unsigned short* __restrict__ y, const float* __restrict__ murs,
    const unsigned short* __restrict__ wbf2, const float* __restrict__ b2,
    unsigned short* __restrict__ ymax, unsigned short* __restrict__ ymin,
    float* __restrict__ stats) {
  __shared__ __align__(16) unsigned short Wl[128 * PITCH2];
  __shared__ __align__(16) unsigned short Gl[128 * PITCH2];
  __shared__ float sa[128], sd[128], sbias[128];
  int bb = blockIdx.y, s0 = blockIdx.x * 4, nh = blockIdx.z, t = threadIdx.x;
  {
    int n = t >> 1, h = t & 1;
    const uint4* wr = (const uint4*)(wbf2 + (size_t)(nh * 128 + n) * 128 + h * 64);
    uint4* wl = (uint4*)(Wl + n * PITCH2 + h * 64);
    #pragma unroll
    for (int i = 0; i < 8; ++i) wl[i] = wr[i];
    if (t < 128) { sa[t] = murs[t * 2]; sd[t] = murs[t * 2 + 1]; sbias[t] = b2[nh * 128 + t]; }
  }
  __syncthreads();
  {
    int r = t >> 1, h = t & 1;
    int q = r >> 5, ks = r & 31;
    size_t qg = (size_t)bb * S_ + s0 + q;
    const ushort4* yr = (const ushort4*)(y + (qg * K_ + ks) * 128 + h * 64);
    #pragma unroll
    for (int i = 0; i < 16; ++i) {
      ushort4 p = yr[i];
      int c = h * 64 + i * 4;
      ushort4 pk;
      pk.x = f2bf(fmaxf(sa[c]     * bf2f(p.x) + sd[c],     0.f));
      pk.y = f2bf(fmaxf(sa[c + 1] * bf2f(p.y) + sd[c + 1], 0.f));
      pk.z = f2bf(fmaxf(sa[c + 2] * bf2f(p.z) + sd[c + 2], 0.f));
      pk.w = f2bf(fmaxf(sa[c + 3] * bf2f(p.w) + sd[c + 3], 0.f));
      *(ushort4*)&Gl[r * PITCH2 + c] = pk;
    }
  }
  __syncthreads();
  int w = t >> 6, L = t & 63, lm = L & 15, lg = L >> 4;
  f32x4 acc[2][8];
  #pragma unroll
  for (int mi = 0; mi < 2; ++mi)
    #pragma unroll
    for (int nt = 0; nt < 8; ++nt) acc[mi][nt] = (f32x4){0.f, 0.f, 0.f, 0.f};
  for (int kt = 0; kt < 4; ++kt) {
    int ko = kt * 32 + lg * 8;
    bf16x8 a0 = *(const bf16x8*)&Gl[(w * 32 + lm) * PITCH2 + ko];
    bf16x8 a1 = *(const bf16x8*)&Gl[(w * 32 + 16 + lm) * PITCH2 + ko];
    bf16x8 bv[8];
    #pragma unroll
    for (int nt = 0; nt < 8; ++nt)
      bv[nt] = *(const bf16x8*)&Wl[(nt * 16 + lm) * PITCH2 + ko];
    #pragma unroll
    for (int nt = 0; nt < 8; ++nt) {
      acc[0][nt] = MFMA(a0, bv[nt], acc[0][nt]);
      acc[1][nt] = MFMA(a1, bv[nt], acc[1][nt]);
    }
  }
  size_t qg = (size_t)bb * S_ + s0 + w;
  int slot = blockIdx.x & 31;
  #pragma unroll
  for (int nt = 0; nt < 8; ++nt) {
    int col = nt * 16 + lm;
    int o = nh * 128 + col;
    float bo = sbias[col];
    float s1 = 0.f, s2 = 0.f, mx = -3.4e38f, mn = 3.4e38f;
    #pragma unroll
    for (int mi = 0; mi < 2; ++mi)
      #pragma unroll
      for (int r = 0; r < 4; ++r) {
        float yv = acc[mi][nt][r] + bo;
        s1 += yv; s2 += yv * yv;
        mx = fmaxf(mx, yv); mn = fminf(mn, yv);
      }
    s1 += __shfl_xor(s1, 16); s2 += __shfl_xor(s2, 16);
    s1 += __shfl_xor(s1, 32); s2 += __shfl_xor(s2, 32);
    mx = fmaxf(mx, __shfl_xor(mx, 16)); mx = fmaxf(mx, __shfl_xor(mx, 32));
    mn = fminf(mn, __shfl_xor(mn, 16)); mn = fminf(mn, __shfl_xor(mn, 32));
    if (lg == 0) {
      ymax[qg * 256 + o] = f2bf(mx);
      ymin[qg * 256 + o] = f2bf(mn);
      atomicAdd(stats + ((size_t)slot * 256 + o) * 2, s1);
      atomicAdd(stats + ((size_t)slot * 256 + o) * 2 + 1, s2);
    }
  }
}

__global__ __launch_bounds__(256) void k_final(const unsigned short* __restrict__ ymax,
                                               const unsigned short* __restrict__ ymin,
                                               const float* __restrict__ murs,
                                               float* __restrict__ out2) {
  __shared__ float tile[32][33];
  int b = blockIdx.z, o0 = blockIdx.y * 32, s0 = blockIdx.x * 32;
  int tx = threadIdx.x, ty = threadIdx.y;
  float a_rd = murs[(o0 + tx) * 2];
  #pragma unroll
  for (int j = 0; j < 32; j += 8) {
    size_t src = ((size_t)b * S_ + s0 + ty + j) * 256 + o0 + tx;
    tile[ty + j][tx] = (a_rd >= 0.0f) ? bf2f(ymax[src]) : bf2f(ymin[src]);
  }
  __syncthreads();
  #pragma unroll
  for (int j = 0; j < 32; j += 8) {
    int o = o0 + ty + j;
    float a = murs[o * 2], dd = murs[o * 2 + 1];
    out2[((size_t)b * 256 + o) * S_ + s0 + tx] = fmaxf(a * tile[tx][ty + j] + dd, 0.0f);
  }
}

extern "C" void kernel_launch(void* const* d_in, const int* in_sizes, int n_in,
                              void* d_out, int out_size, void* d_ws, size_t ws_size,
                              hipStream_t stream) {
  (void)in_sizes; (void)n_in; (void)out_size; (void)ws_size;
  const float* xyz  = (const float*)d_in[0];
  const float* feat = (const float*)d_in[1];
  const float* w0   = (const float*)d_in[2];
  const float* b0   = (const float*)d_in[3];
  const float* ga0  = (const float*)d_in[4];
  const float* be0  = (const float*)d_in[5];
  const float* w1   = (const float*)d_in[6];
  const float* b1   = (const float*)d_in[7];
  const float* ga1  = (const float*)d_in[8];
  const float* be1  = (const float*)d_in[9];
  const float* w2   = (const float*)d_in[10];
  const float* b2   = (const float*)d_in[11];
  const float* ga2  = (const float*)d_in[12];
  const float* be2  = (const float*)d_in[13];

  float* out_xyz  = (float*)d_out;
  float* out_feat = out_xyz + (size_t)B_ * S_ * 3;

  char* ws = (char*)d_ws;
  size_t off = 0;
  auto alloc = [&](size_t bytes) -> void* {
    void* p = ws + off;
    off += (bytes + 255) & ~(size_t)255;
    return p;
  };
  unsigned short* featT = (unsigned short*)alloc((size_t)B_ * N_ * 128 * 2);  // 16.8 MB bf16
  float* stats = (float*)alloc(32768 * 4);
  float* murs1 = (float*)alloc(128 * 2 * 4);
  float* murs2 = (float*)alloc(128 * 2 * 4);
  float* murs3 = (float*)alloc(256 * 2 * 4);
  unsigned short* wbf0 = (unsigned short*)alloc(128 * 160 * 2);
  unsigned short* wbf1 = (unsigned short*)alloc(128 * 128 * 2);
  unsigned short* wbf2 = (unsigned short*)alloc(256 * 128 * 2);
  unsigned short* ymaxb = (unsigned short*)alloc((size_t)B_ * S_ * 256 * 2);  // 8.4 MB
  unsigned short* yminb = (unsigned short*)alloc((size_t)B_ * S_ * 256 * 2);  // 8.4 MB
  unsigned short* y = (unsigned short*)alloc((size_t)B_ * S_ * K_ * 128 * 2); // 134 MB

  // blocks: 16 fps | 16 init | 8192 transpose
  k_front<<<16 + 16 + 8192, 512, 0, stream>>>(xyz, out_xyz, feat, featT,
                                              w0, w1, w2, wbf0, wbf1, wbf2, stats);
  k_layer1<<<dim3(256, 16), 256, 0, stream>>>(xyz, out_xyz, featT, wbf0, b0, y, stats);
  k_finalize<<<1, 256, 0, stream>>>(stats, ga0, be0, murs1, 128);
  k_layer2<<<dim3(256, 16), 256, 0, stream>>>(y, murs1, wbf1, b1, stats + 8192);
  k_finalize<<<1, 256, 0, stream>>>(stats + 8192, ga1, be1, murs2, 128);
  k_layer3<<<dim3(256, 16, 2), 256, 0, stream>>>(y, murs2, wbf2, b2, ymaxb, yminb, stats + 16384);
  k_finalize<<<1, 256, 0, stream>>>(stats + 16384, ga2, be2, murs3, 256);
  k_final<<<dim3(32, 8, 16), dim3(32, 8), 0, stream>>>(ymaxb, yminb, murs3, out_feat);
}

// Round 9
// 1211.024 us; speedup vs baseline: 1.2132x; 1.2132x over previous
//
#include <hip/hip_runtime.h>

#define B_ 16
#define N_ 4096
#define S_ 1024
#define K_ 32
#define PITCH2 136   // 128 + 8 shorts: b128 frag reads -> 2-way bank alias (free)
#define PITCH1 168   // 160 + 8 shorts
#define OPITCH 136   // output-tile pitch for epilogue transpose

typedef unsigned long long u64;
typedef short bf16x8 __attribute__((ext_vector_type(8)));
typedef float f32x4 __attribute__((ext_vector_type(4)));
typedef float f32x2 __attribute__((ext_vector_type(2)));

__device__ __forceinline__ unsigned short f2bf(float f) {
  unsigned u = __float_as_uint(f);
  unsigned r = (u + 0x7FFFu + ((u >> 16) & 1u)) >> 16;
  return (unsigned short)r;
}
__device__ __forceinline__ float bf2f(unsigned short h) {
  return __uint_as_float(((unsigned)h) << 16);
}

// DPP wave64 max reduce: shr1,2,4,8 + bcast15 + bcast31 -> lane 63 = wave max
#define DPP_MAX(v, ctrl)                                                        \
  {                                                                             \
    int _t = __builtin_amdgcn_update_dpp(__float_as_int(v), __float_as_int(v),  \
                                         ctrl, 0xf, 0xf, false);                \
    v = fmaxf(v, __int_as_float(_t));                                           \
  }

// ===== fused front kernel: blocks 0-15 FPS | 16-31 init | 32+ transpose =====
__global__ __launch_bounds__(512) void k_front(
    const float* __restrict__ xyz, float* __restrict__ new_xyz,
    const float* __restrict__ feat, unsigned short* __restrict__ featT,
    const float* __restrict__ w0, const float* __restrict__ w1,
    const float* __restrict__ w2, unsigned short* __restrict__ wbf0,
    unsigned short* __restrict__ wbf1, unsigned short* __restrict__ wbf2,
    float* __restrict__ stats) {
  __shared__ __align__(16) float smem[N_ * 4 + S_ + 64];  // 64KB pts + 4KB idxs + keys
  int blk = blockIdx.x, t = threadIdx.x;

  if (blk < 16) {
#pragma clang fp contract(off)
    // ---------------- farthest point sampling ----------------
#if __has_builtin(__builtin_amdgcn_s_setprio)
    __builtin_amdgcn_s_setprio(3);
#endif
    float4* pts = (float4*)smem;              // [4096]
    int* idxs = (int*)(smem + N_ * 4);        // [1024]
    u64* swk = (u64*)(smem + N_ * 4 + S_);    // [2][8]
    int b = blk;
    const float* base = xyz + (size_t)b * N_ * 3;
    for (int i = t; i < N_; i += 512)
      pts[i] = make_float4(base[i * 3], base[i * 3 + 1], base[i * 3 + 2], 0.0f);
    if (t == 0) idxs[0] = 0;
    __syncthreads();
    f32x2 px[4], py[4], pz[4], pd[4];
    int i0 = t * 8;
    #pragma unroll
    for (int j = 0; j < 4; ++j) {
      float4 p0 = pts[i0 + 2 * j], p1 = pts[i0 + 2 * j + 1];
      px[j] = (f32x2){p0.x, p1.x};
      py[j] = (f32x2){p0.y, p1.y};
      pz[j] = (f32x2){p0.z, p1.z};
      pd[j] = (f32x2){1e10f, 1e10f};
    }
    int cur = 0;
    for (int it = 0; it < S_; ++it) {
      float4 c = pts[cur];
      f32x2 c2x = (f32x2){c.x, c.x}, c2y = (f32x2){c.y, c.y}, c2z = (f32x2){c.z, c.z};
      float bestv = -1.0f; int besti = 0;
      #pragma unroll
      for (int j = 0; j < 4; ++j) {
        f32x2 dx = px[j] - c2x;
        f32x2 dy = py[j] - c2y;
        f32x2 dz = pz[j] - c2z;
        f32x2 d = (dx * dx + dy * dy) + dz * dz;
        f32x2 dm = __builtin_elementwise_min(pd[j], d);
        pd[j] = dm;
        if (dm.x > bestv) { bestv = dm.x; besti = 2 * j; }
        if (dm.y > bestv) { bestv = dm.y; besti = 2 * j + 1; }
      }
      float v = bestv;
      DPP_MAX(v, 0x111);
      DPP_MAX(v, 0x112);
      DPP_MAX(v, 0x114);
      DPP_MAX(v, 0x118);
      DPP_MAX(v, 0x142);
      DPP_MAX(v, 0x143);
      float wmax = __int_as_float(__builtin_amdgcn_readlane(__float_as_int(v), 63));
      u64 mask = __ballot(bestv == wmax);
      int owner = __ffsll((long long)mask) - 1;
      int widx = __builtin_amdgcn_readlane(i0 + besti, owner);
      if ((t & 63) == 0)
        swk[(it & 1) * 8 + (t >> 6)] =
            ((u64)__float_as_uint(wmax) << 32) | (unsigned)(4095 - widx);
      __syncthreads();
      const u64* kk = swk + (it & 1) * 8;
      u64 k0 = kk[0];
      #pragma unroll
      for (int w = 1; w < 8; ++w) if (kk[w] > k0) k0 = kk[w];
      cur = 4095 - (int)(unsigned)(k0 & 0xFFFFFFFFull);
      if (t == 0 && it + 1 < S_) idxs[it + 1] = cur;
    }
    __syncthreads();
    for (int i = t; i < S_; i += 512) {
      float4 v = pts[idxs[i]];
      size_t o = ((size_t)b * S_ + i) * 3;
      new_xyz[o] = v.x; new_xyz[o + 1] = v.y; new_xyz[o + 2] = v.z;
    }
  } else if (blk < 32) {
    // ---------------- init: zero stats, weights -> bf16 [n][k] ----------------
    int id = (blk - 16) * 512 + t;
    const int st = 16 * 512;
    for (int i = id; i < 32768; i += st) stats[i] = 0.0f;
    for (int i = id; i < 128 * 160; i += st) {
      int n = i / 160, k = i - n * 160;
      float v = (k < 128) ? w0[n * 131 + 3 + k] : (k < 131) ? w0[n * 131 + k - 128] : 0.0f;
      wbf0[i] = f2bf(v);
    }
    for (int i = id; i < 128 * 128; i += st) wbf1[i] = f2bf(w1[i]);
    for (int i = id; i < 256 * 128; i += st) wbf2[i] = f2bf(w2[i]);
  } else {
    // ------------- transpose features (B,C,N) f32 -> (B,N,C) bf16 -------------
    float (*tile)[33] = (float(*)[33])smem;
    int blk2 = blk - 32;
    int n0 = (blk2 & 127) * 32;
    int c0 = ((blk2 >> 7) & 3) * 32;
    int b = blk2 >> 9;
    int tx = t & 31, ty = t >> 5;
    #pragma unroll
    for (int j = 0; j < 32; j += 16)
      tile[ty + j][tx] = feat[((size_t)b * 128 + c0 + ty + j) * N_ + n0 + tx];
    __syncthreads();
    #pragma unroll
    for (int j = 0; j < 32; j += 16)
      featT[((size_t)b * N_ + n0 + ty + j) * 128 + c0 + tx] = f2bf(tile[tx][ty + j]);
  }
}

// ---------------- ball query (standalone again -- r8's fusion into the
// 1-block/CU layer1 exposed the latency-bound scan; here 8+ slim blocks/CU
// hide it) ----------------
__global__ __launch_bounds__(256) void k_ballq(const float* __restrict__ xyz,
                                               const float* __restrict__ new_xyz,
                                               int* __restrict__ ball_idx) {
  int b = blockIdx.y;
  int s = blockIdx.x * 4 + (threadIdx.x >> 6);
  int lane = threadIdx.x & 63;
  const float* pb = xyz + (size_t)b * N_ * 3;
  size_t q = (size_t)b * S_ + s;
  float qx = new_xyz[q * 3], qy = new_xyz[q * 3 + 1], qz = new_xyz[q * 3 + 2];
  float sq = __fadd_rn(__fadd_rn(__fmul_rn(qx, qx), __fmul_rn(qy, qy)), __fmul_rn(qz, qz));
  int* out = ball_idx + q * K_;
  int total = 0;
  int first_idx = -1;
  for (int basei = 0; basei < N_; basei += 64) {
    int i = basei + lane;
    float fx = pb[i * 3], fy = pb[i * 3 + 1], fz = pb[i * 3 + 2];
    float dot = __fmul_rn(qx, fx);
    dot = __fadd_rn(dot, __fmul_rn(qy, fy));
    dot = __fadd_rn(dot, __fmul_rn(qz, fz));
    float sd = __fadd_rn(__fadd_rn(__fmul_rn(fx, fx), __fmul_rn(fy, fy)), __fmul_rn(fz, fz));
    float dist = __fadd_rn(__fadd_rn(__fmul_rn(-2.0f, dot), sq), sd);
    bool within = (dist <= 0.36f);
    u64 m = __ballot(within);
    if (first_idx < 0 && m) first_idx = basei + __ffsll((long long)m) - 1;
    if (within) {
      int pos = total + __popcll(m & ((1ull << lane) - 1ull));
      if (pos < K_) out[pos] = i;
    }
    total += (int)__popcll(m);
    if (total >= K_) break;
  }
  if (total < K_) {
    int k2 = total + lane;
    if (k2 < K_) out[k2] = first_idx;
  }
}

// ============ MFMA layer kernels ============
#define MFMA(a, b, c) __builtin_amdgcn_mfma_f32_16x16x32_bf16(a, b, c, 0, 0, 0)

// ---- layer 1: gather + matmul K=131(pad160)->128; coalesced epilogue ----
__global__ __launch_bounds__(256) void k_layer1(
    const float* __restrict__ xyz, const float* __restrict__ new_xyz,
    const unsigned short* __restrict__ featT, const int* __restrict__ ball_idx,
    const unsigned short* __restrict__ wbf0, const float* __restrict__ b0,
    unsigned short* __restrict__ y, float* __restrict__ stats) {
  __shared__ __align__(16) unsigned short Wl[128 * PITCH1];
  __shared__ __align__(16) unsigned short Gl[128 * PITCH1];
  __shared__ float sbias[128];
  int bb = blockIdx.y, s0 = blockIdx.x * 4, t = threadIdx.x;
  {
    int n = t >> 1, h = t & 1;
    const uint4* wr = (const uint4*)(wbf0 + n * 160 + h * 80);
    uint4* wl = (uint4*)(Wl + n * PITCH1 + h * 80);
    #pragma unroll
    for (int i = 0; i < 10; ++i) wl[i] = wr[i];
    if (t < 128) sbias[t] = b0[t];
  }
  {
    int r = t >> 1, h = t & 1;
    int ks = r & 31;
    size_t qg = (size_t)bb * S_ + s0 + (r >> 5);
    int p = ball_idx[qg * K_ + ks];
    const uint4* fr = (const uint4*)(featT + ((size_t)bb * N_ + p) * 128 + h * 64);
    uint4* gr = (uint4*)(Gl + r * PITCH1 + h * 64);
    #pragma unroll
    for (int i = 0; i < 8; ++i) gr[i] = fr[i];
    if (h == 0) {
      const float* pp = xyz + ((size_t)bb * N_ + p) * 3;
      Gl[r * PITCH1 + 128] = f2bf(pp[0] - new_xyz[qg * 3]);
      Gl[r * PITCH1 + 129] = f2bf(pp[1] - new_xyz[qg * 3 + 1]);
      Gl[r * PITCH1 + 130] = f2bf(pp[2] - new_xyz[qg * 3 + 2]);
    } else {
      for (int k = 131; k < 160; ++k) Gl[r * PITCH1 + k] = 0;
    }
  }
  __syncthreads();
  int w = t >> 6, L = t & 63, lm = L & 15, lg = L >> 4;
  f32x4 acc[2][8];
  #pragma unroll
  for (int mi = 0; mi < 2; ++mi)
    #pragma unroll
    for (int nt = 0; nt < 8; ++nt) acc[mi][nt] = (f32x4){0.f, 0.f, 0.f, 0.f};
  for (int kt = 0; kt < 5; ++kt) {
    int ko = kt * 32 + lg * 8;
    bf16x8 a0 = *(const bf16x8*)&Gl[(w * 32 + lm) * PITCH1 + ko];
    bf16x8 a1 = *(const bf16x8*)&Gl[(w * 32 + 16 + lm) * PITCH1 + ko];
    bf16x8 bv[8];
    #pragma unroll
    for (int nt = 0; nt < 8; ++nt)
      bv[nt] = *(const bf16x8*)&Wl[(nt * 16 + lm) * PITCH1 + ko];
    #pragma unroll
    for (int nt = 0; nt < 8; ++nt) {
      acc[0][nt] = MFMA(a0, bv[nt], acc[0][nt]);
      acc[1][nt] = MFMA(a1, bv[nt], acc[1][nt]);
    }
  }
  // ---- epilogue: stats + LDS transpose (wave writes only its own rows) ----
  int slot = blockIdx.x & 31;
  #pragma unroll
  for (int nt = 0; nt < 8; ++nt) {
    int col = nt * 16 + lm;
    float bo = sbias[col];
    float s1 = 0.f, s2 = 0.f;
    #pragma unroll
    for (int mi = 0; mi < 2; ++mi)
      #pragma unroll
      for (int r = 0; r < 4; ++r) {
        float yv = acc[mi][nt][r] + bo;
        s1 += yv; s2 += yv * yv;
        int rr = w * 32 + mi * 16 + lg * 4 + r;
        Gl[rr * OPITCH + col] = f2bf(yv);
      }
    s1 += __shfl_xor(s1, 16); s2 += __shfl_xor(s2, 16);
    s1 += __shfl_xor(s1, 32); s2 += __shfl_xor(s2, 32);
    if (lg == 0) {
      atomicAdd(stats + ((size_t)slot * 128 + col) * 2, s1);
      atomicAdd(stats + ((size_t)slot * 128 + col) * 2 + 1, s2);
    }
  }
  __syncthreads();
  // ---- coalesced streaming store of the 128x128 tile ----
  {
    int rr = t >> 1, ch = (t & 1) * 64;
    const uint4* src = (const uint4*)&Gl[rr * OPITCH + ch];
    uint4* dst = (uint4*)(y + (((size_t)bb * S_ + s0) * K_ + rr) * 128 + ch);
    #pragma unroll
    for (int i = 0; i < 8; ++i) dst[i] = src[i];
  }
}

__global__ void k_finalize(const float* __restrict__ stats, const float* __restrict__ gamma,
                           const float* __restrict__ beta, float* __restrict__ murs, int C) {
  for (int c = threadIdx.x; c < C; c += blockDim.x) {
    float s1 = 0.0f, s2 = 0.0f;
    for (int sl = 0; sl < 32; ++sl) {
      s1 += stats[((size_t)sl * C + c) * 2];
      s2 += stats[((size_t)sl * C + c) * 2 + 1];
    }
    const float inv = 1.0f / 524288.0f;  // 2^-19, exact
    float mu = s1 * inv;
    float var = s2 * inv - mu * mu;
    float a = gamma[c] * rsqrtf(var + 1e-5f);
    murs[c * 2] = a;
    murs[c * 2 + 1] = beta[c] - a * mu;
  }
}

// ---- layer 2: BN+relu(y) -> matmul 128->128, y IN-PLACE, coalesced stores ----
__global__ __launch_bounds__(256) void k_layer2(
    unsigned short* y, const float* __restrict__ murs,
    const unsigned short* __restrict__ wbf1, const float* __restrict__ b1,
    float* __restrict__ stats) {
  __shared__ __align__(16) unsigned short Wl[128 * PITCH2];
  __shared__ __align__(16) unsigned short Gl[128 * PITCH2];
  __shared__ float sa[128], sd[128], sbias[128];
  int bb = blockIdx.y, s0 = blockIdx.x * 4, t = threadIdx.x;
  {
    int n = t >> 1, h = t & 1;
    const uint4* wr = (const uint4*)(wbf1 + n * 128 + h * 64);
    uint4* wl = (uint4*)(Wl + n * PITCH2 + h * 64);
    #pragma unroll
    for (int i = 0; i < 8; ++i) wl[i] = wr[i];
    if (t < 128) { sa[t] = murs[t * 2]; sd[t] = murs[t * 2 + 1]; sbias[t] = b1[t]; }
  }
  __syncthreads();
  {
    int r = t >> 1, h = t & 1;
    int q = r >> 5, ks = r & 31;
    size_t qg = (size_t)bb * S_ + s0 + q;
    const ushort4* yr = (const ushort4*)(y + (qg * K_ + ks) * 128 + h * 64);
    #pragma unroll
    for (int i = 0; i < 16; ++i) {
      ushort4 p = yr[i];
      int c = h * 64 + i * 4;
      ushort4 pk;
      pk.x = f2bf(fmaxf(sa[c]     * bf2f(p.x) + sd[c],     0.f));
      pk.y = f2bf(fmaxf(sa[c + 1] * bf2f(p.y) + sd[c + 1], 0.f));
      pk.z = f2bf(fmaxf(sa[c + 2] * bf2f(p.z) + sd[c + 2], 0.f));
      pk.w = f2bf(fmaxf(sa[c + 3] * bf2f(p.w) + sd[c + 3], 0.f));
      *(ushort4*)&Gl[r * PITCH2 + c] = pk;
    }
  }
  __syncthreads();
  int w = t >> 6, L = t & 63, lm = L & 15, lg = L >> 4;
  f32x4 acc[2][8];
  #pragma unroll
  for (int mi = 0; mi < 2; ++mi)
    #pragma unroll
    for (int nt = 0; nt < 8; ++nt) acc[mi][nt] = (f32x4){0.f, 0.f, 0.f, 0.f};
  for (int kt = 0; kt < 4; ++kt) {
    int ko = kt * 32 + lg * 8;
    bf16x8 a0 = *(const bf16x8*)&Gl[(w * 32 + lm) * PITCH2 + ko];
    bf16x8 a1 = *(const bf16x8*)&Gl[(w * 32 + 16 + lm) * PITCH2 + ko];
    bf16x8 bv[8];
    #pragma unroll
    for (int nt = 0; nt < 8; ++nt)
      bv[nt] = *(const bf16x8*)&Wl[(nt * 16 + lm) * PITCH2 + ko];
    #pragma unroll
    for (int nt = 0; nt < 8; ++nt) {
      acc[0][nt] = MFMA(a0, bv[nt], acc[0][nt]);
      acc[1][nt] = MFMA(a1, bv[nt], acc[1][nt]);
    }
  }
  int slot = blockIdx.x & 31;
  #pragma unroll
  for (int nt = 0; nt < 8; ++nt) {
    int col = nt * 16 + lm;
    float bo = sbias[col];
    float s1 = 0.f, s2 = 0.f;
    #pragma unroll
    for (int mi = 0; mi < 2; ++mi)
      #pragma unroll
      for (int r = 0; r < 4; ++r) {
        float yv = acc[mi][nt][r] + bo;
        s1 += yv; s2 += yv * yv;
        int rr = w * 32 + mi * 16 + lg * 4 + r;
        Gl[rr * OPITCH + col] = f2bf(yv);
      }
    s1 += __shfl_xor(s1, 16); s2 += __shfl_xor(s2, 16);
    s1 += __shfl_xor(s1, 32); s2 += __shfl_xor(s2, 32);
    if (lg == 0) {
      atomicAdd(stats + ((size_t)slot * 128 + col) * 2, s1);
      atomicAdd(stats + ((size_t)slot * 128 + col) * 2 + 1, s2);
    }
  }
  __syncthreads();
  {
    int rr = t >> 1, ch = (t & 1) * 64;
    const uint4* src = (const uint4*)&Gl[rr * OPITCH + ch];
    uint4* dst = (uint4*)(y + (((size_t)bb * S_ + s0) * K_ + rr) * 128 + ch);
    #pragma unroll
    for (int i = 0; i < 8; ++i) dst[i] = src[i];
  }
}

// ---- layer 3: BN+relu(y) -> matmul 128->256 (N split by blockIdx.z) ----
__global__ __launch_bounds__(256) void k_layer3(
    const unsigned short* __restrict__ y, const float* __restrict__ murs,
    const unsigned short* __restrict__ wbf2, const float* __restrict__ b2,
    unsigned short* __restrict__ ymax, unsigned short* __restrict__ ymin,
    float* __restrict__ stats) {
  __shared__ __align__(16) unsigned short Wl[128 * PITCH2];
  __shared__ __align__(16) unsigned short Gl[128 * PITCH2];
  __shared__ float sa[128], sd[128], sbias[128];
  int bb = blockIdx.y, s0 = blockIdx.x * 4, nh = blockIdx.z, t = threadIdx.x;
  {
    int n = t >> 1, h = t & 1;
    const uint4* wr = (const uint4*)(wbf2 + (size_t)(nh * 128 + n) * 128 + h * 64);
    uint4* wl = (uint4*)(Wl + n * PITCH2 + h * 64);
    #pragma unroll
    for (int i = 0; i < 8; ++i) wl[i] = wr[i];
    if (t < 128) { sa[t] = murs[t * 2]; sd[t] = murs[t * 2 + 1]; sbias[t] = b2[nh * 128 + t]; }
  }
  __syncthreads();
  {
    int r = t >> 1, h = t & 1;
    int q = r >> 5, ks = r & 31;
    size_t qg = (size_t)bb * S_ + s0 + q;
    const ushort4* yr = (const ushort4*)(y + (qg * K_ + ks) * 128 + h * 64);
    #pragma unroll
    for (int i = 0; i < 16; ++i) {
      ushort4 p = yr[i];
      int c = h * 64 + i * 4;
      ushort4 pk;
      pk.x = f2bf(fmaxf(sa[c]     * bf2f(p.x) + sd[c],     0.f));
      pk.y = f2bf(fmaxf(sa[c + 1] * bf2f(p.y) + sd[c + 1], 0.f));
      pk.z = f2bf(fmaxf(sa[c + 2] * bf2f(p.z) + sd[c + 2], 0.f));
      pk.w = f2bf(fmaxf(sa[c + 3] * bf2f(p.w) + sd[c + 3], 0.f));
      *(ushort4*)&Gl[r * PITCH2 + c] = pk;
    }
  }
  __syncthreads();
  int w = t >> 6, L = t & 63, lm = L & 15, lg = L >> 4;
  f32x4 acc[2][8];
  #pragma unroll
  for (int mi = 0; mi < 2; ++mi)
    #pragma unroll
    for (int nt = 0; nt < 8; ++nt) acc[mi][nt] = (f32x4){0.f, 0.f, 0.f, 0.f};
  for (int kt = 0; kt < 4; ++kt) {
    int ko = kt * 32 + lg * 8;
    bf16x8 a0 = *(const bf16x8*)&Gl[(w * 32 + lm) * PITCH2 + ko];
    bf16x8 a1 = *(const bf16x8*)&Gl[(w * 32 + 16 + lm) * PITCH2 + ko];
    bf16x8 bv[8];
    #pragma unroll
    for (int nt = 0; nt < 8; ++nt)
      bv[nt] = *(const bf16x8*)&Wl[(nt * 16 + lm) * PITCH2 + ko];
    #pragma unroll
    for (int nt = 0; nt < 8; ++nt) {
      acc[0][nt] = MFMA(a0, bv[nt], acc[0][nt]);
      acc[1][nt] = MFMA(a1, bv[nt], acc[1][nt]);
    }
  }
  size_t qg = (size_t)bb * S_ + s0 + w;
  int slot = blockIdx.x & 31;
  #pragma unroll
  for (int nt = 0; nt < 8; ++nt) {
    int col = nt * 16 + lm;
    int o = nh * 128 + col;
    float bo = sbias[col];
    float s1 = 0.f, s2 = 0.f, mx = -3.4e38f, mn = 3.4e38f;
    #pragma unroll
    for (int mi = 0; mi < 2; ++mi)
      #pragma unroll
      for (int r = 0; r < 4; ++r) {
        float yv = acc[mi][nt][r] + bo;
        s1 += yv; s2 += yv * yv;
        mx = fmaxf(mx, yv); mn = fminf(mn, yv);
      }
    s1 += __shfl_xor(s1, 16); s2 += __shfl_xor(s2, 16);
    s1 += __shfl_xor(s1, 32); s2 += __shfl_xor(s2, 32);
    mx = fmaxf(mx, __shfl_xor(mx, 16)); mx = fmaxf(mx, __shfl_xor(mx, 32));
    mn = fminf(mn, __shfl_xor(mn, 16)); mn = fminf(mn, __shfl_xor(mn, 32));
    if (lg == 0) {
      ymax[qg * 256 + o] = f2bf(mx);
      ymin[qg * 256 + o] = f2bf(mn);
      atomicAdd(stats + ((size_t)slot * 256 + o) * 2, s1);
      atomicAdd(stats + ((size_t)slot * 256 + o) * 2 + 1, s2);
    }
  }
}

__global__ __launch_bounds__(256) void k_final(const unsigned short* __restrict__ ymax,
                                               const unsigned short* __restrict__ ymin,
                                               const float* __restrict__ murs,
                                               float* __restrict__ out2) {
  __shared__ float tile[32][33];
  int b = blockIdx.z, o0 = blockIdx.y * 32, s0 = blockIdx.x * 32;
  int tx = threadIdx.x, ty = threadIdx.y;
  float a_rd = murs[(o0 + tx) * 2];
  #pragma unroll
  for (int j = 0; j < 32; j += 8) {
    size_t src = ((size_t)b * S_ + s0 + ty + j) * 256 + o0 + tx;
    tile[ty + j][tx] = (a_rd >= 0.0f) ? bf2f(ymax[src]) : bf2f(ymin[src]);
  }
  __syncthreads();
  #pragma unroll
  for (int j = 0; j < 32; j += 8) {
    int o = o0 + ty + j;
    float a = murs[o * 2], dd = murs[o * 2 + 1];
    out2[((size_t)b * 256 + o) * S_ + s0 + tx] = fmaxf(a * tile[tx][ty + j] + dd, 0.0f);
  }
}

extern "C" void kernel_launch(void* const* d_in, const int* in_sizes, int n_in,
                              void* d_out, int out_size, void* d_ws, size_t ws_size,
                              hipStream_t stream) {
  (void)in_sizes; (void)n_in; (void)out_size; (void)ws_size;
  const float* xyz  = (const float*)d_in[0];
  const float* feat = (const float*)d_in[1];
  const float* w0   = (const float*)d_in[2];
  const float* b0   = (const float*)d_in[3];
  const float* ga0  = (const float*)d_in[4];
  const float* be0  = (const float*)d_in[5];
  const float* w1   = (const float*)d_in[6];
  const float* b1   = (const float*)d_in[7];
  const float* ga1  = (const float*)d_in[8];
  const float* be1  = (const float*)d_in[9];
  const float* w2   = (const float*)d_in[10];
  const float* b2   = (const float*)d_in[11];
  const float* ga2  = (const float*)d_in[12];
  const float* be2  = (const float*)d_in[13];

  float* out_xyz  = (float*)d_out;
  float* out_feat = out_xyz + (size_t)B_ * S_ * 3;

  char* ws = (char*)d_ws;
  size_t off = 0;
  auto alloc = [&](size_t bytes) -> void* {
    void* p = ws + off;
    off += (bytes + 255) & ~(size_t)255;
    return p;
  };
  unsigned short* featT = (unsigned short*)alloc((size_t)B_ * N_ * 128 * 2);  // 16.8 MB bf16
  int*   ball  = (int*)alloc((size_t)B_ * S_ * K_ * 4);                       // 2.1 MB
  float* stats = (float*)alloc(32768 * 4);
  float* murs1 = (float*)alloc(128 * 2 * 4);
  float* murs2 = (float*)alloc(128 * 2 * 4);
  float* murs3 = (float*)alloc(256 * 2 * 4);
  unsigned short* wbf0 = (unsigned short*)alloc(128 * 160 * 2);
  unsigned short* wbf1 = (unsigned short*)alloc(128 * 128 * 2);
  unsigned short* wbf2 = (unsigned short*)alloc(256 * 128 * 2);
  unsigned short* ymaxb = (unsigned short*)alloc((size_t)B_ * S_ * 256 * 2);  // 8.4 MB
  unsigned short* yminb = (unsigned short*)alloc((size_t)B_ * S_ * 256 * 2);  // 8.4 MB
  unsigned short* y = (unsigned short*)alloc((size_t)B_ * S_ * K_ * 128 * 2); // 134 MB

  // blocks: 16 fps | 16 init | 8192 transpose
  k_front<<<16 + 16 + 8192, 512, 0, stream>>>(xyz, out_xyz, feat, featT,
                                              w0, w1, w2, wbf0, wbf1, wbf2, stats);
  k_ballq<<<dim3(256, 16), 256, 0, stream>>>(xyz, out_xyz, ball);
  k_layer1<<<dim3(256, 16), 256, 0, stream>>>(xyz, out_xyz, featT, ball, wbf0, b0, y, stats);
  k_finalize<<<1, 256, 0, stream>>>(stats, ga0, be0, murs1, 128);
  k_layer2<<<dim3(256, 16), 256, 0, stream>>>(y, murs1, wbf1, b1, stats + 8192);
  k_finalize<<<1, 256, 0, stream>>>(stats + 8192, ga1, be1, murs2, 128);
  k_layer3<<<dim3(256, 16, 2), 256, 0, stream>>>(y, murs2, wbf2, b2, ymaxb, yminb, stats + 16384);
  k_finalize<<<1, 256, 0, stream>>>(stats + 16384, ga2, be2, murs3, 256);
  k_final<<<dim3(32, 8, 16), dim3(32, 8), 0, stream>>>(ymaxb, yminb, murs3, out_feat);
}

// Round 10
// 1133.191 us; speedup vs baseline: 1.2965x; 1.0687x over previous
//
#include <hip/hip_runtime.h>

#define B_ 16
#define N_ 4096
#define S_ 1024
#define K_ 32
#define PITCH2 136   // 128 + 8 shorts: b128 frag reads -> 2-way bank alias (free)
#define PITCH1 168   // 160 + 8 shorts

typedef unsigned long long u64;
typedef short bf16x8 __attribute__((ext_vector_type(8)));
typedef unsigned short u16x8 __attribute__((ext_vector_type(8)));
typedef float f32x4 __attribute__((ext_vector_type(4)));
typedef float f32x2 __attribute__((ext_vector_type(2)));

__device__ __forceinline__ unsigned short f2bf(float f) {
  unsigned u = __float_as_uint(f);
  unsigned r = (u + 0x7FFFu + ((u >> 16) & 1u)) >> 16;
  return (unsigned short)r;
}
__device__ __forceinline__ float bf2f(unsigned short h) {
  return __uint_as_float(((unsigned)h) << 16);
}

// DPP wave64 max reduce: shr1,2,4,8 + bcast15 + bcast31 -> lane 63 = wave max
#define DPP_MAX(v, ctrl)                                                        \
  {                                                                             \
    int _t = __builtin_amdgcn_update_dpp(__float_as_int(v), __float_as_int(v),  \
                                         ctrl, 0xf, 0xf, false);                \
    v = fmaxf(v, __int_as_float(_t));                                           \
  }

// ===== fused front kernel: blocks 0-15 FPS | 16-31 init | 32+ transpose =====
__global__ __launch_bounds__(512) void k_front(
    const float* __restrict__ xyz, float* __restrict__ new_xyz,
    const float* __restrict__ feat, unsigned short* __restrict__ featT,
    const float* __restrict__ w0, const float* __restrict__ w1,
    const float* __restrict__ w2, unsigned short* __restrict__ wbf0,
    unsigned short* __restrict__ wbf1, unsigned short* __restrict__ wbf2,
    float* __restrict__ stats) {
  __shared__ __align__(16) float smem[N_ * 4 + S_ + 64];
  int blk = blockIdx.x, t = threadIdx.x;

  if (blk < 16) {
#pragma clang fp contract(off)
#if __has_builtin(__builtin_amdgcn_s_setprio)
    __builtin_amdgcn_s_setprio(3);
#endif
    float4* pts = (float4*)smem;
    int* idxs = (int*)(smem + N_ * 4);
    u64* swk = (u64*)(smem + N_ * 4 + S_);
    int b = blk;
    const float* base = xyz + (size_t)b * N_ * 3;
    for (int i = t; i < N_; i += 512)
      pts[i] = make_float4(base[i * 3], base[i * 3 + 1], base[i * 3 + 2], 0.0f);
    if (t == 0) idxs[0] = 0;
    __syncthreads();
    f32x2 px[4], py[4], pz[4], pd[4];
    int i0 = t * 8;
    #pragma unroll
    for (int j = 0; j < 4; ++j) {
      float4 p0 = pts[i0 + 2 * j], p1 = pts[i0 + 2 * j + 1];
      px[j] = (f32x2){p0.x, p1.x};
      py[j] = (f32x2){p0.y, p1.y};
      pz[j] = (f32x2){p0.z, p1.z};
      pd[j] = (f32x2){1e10f, 1e10f};
    }
    int cur = 0;
    for (int it = 0; it < S_; ++it) {
      float4 c = pts[cur];
      f32x2 c2x = (f32x2){c.x, c.x}, c2y = (f32x2){c.y, c.y}, c2z = (f32x2){c.z, c.z};
      float bestv = -1.0f; int besti = 0;
      #pragma unroll
      for (int j = 0; j < 4; ++j) {
        f32x2 dx = px[j] - c2x;
        f32x2 dy = py[j] - c2y;
        f32x2 dz = pz[j] - c2z;
        f32x2 d = (dx * dx + dy * dy) + dz * dz;
        f32x2 dm = __builtin_elementwise_min(pd[j], d);
        pd[j] = dm;
        if (dm.x > bestv) { bestv = dm.x; besti = 2 * j; }
        if (dm.y > bestv) { bestv = dm.y; besti = 2 * j + 1; }
      }
      float v = bestv;
      DPP_MAX(v, 0x111);
      DPP_MAX(v, 0x112);
      DPP_MAX(v, 0x114);
      DPP_MAX(v, 0x118);
      DPP_MAX(v, 0x142);
      DPP_MAX(v, 0x143);
      float wmax = __int_as_float(__builtin_amdgcn_readlane(__float_as_int(v), 63));
      u64 mask = __ballot(bestv == wmax);
      int owner = __ffsll((long long)mask) - 1;
      int widx = __builtin_amdgcn_readlane(i0 + besti, owner);
      if ((t & 63) == 0)
        swk[(it & 1) * 8 + (t >> 6)] =
            ((u64)__float_as_uint(wmax) << 32) | (unsigned)(4095 - widx);
      __syncthreads();
      const u64* kk = swk + (it & 1) * 8;
      u64 k0 = kk[0];
      #pragma unroll
      for (int w = 1; w < 8; ++w) if (kk[w] > k0) k0 = kk[w];
      cur = 4095 - (int)(unsigned)(k0 & 0xFFFFFFFFull);
      if (t == 0 && it + 1 < S_) idxs[it + 1] = cur;
    }
    __syncthreads();
    for (int i = t; i < S_; i += 512) {
      float4 v = pts[idxs[i]];
      size_t o = ((size_t)b * S_ + i) * 3;
      new_xyz[o] = v.x; new_xyz[o + 1] = v.y; new_xyz[o + 2] = v.z;
    }
  } else if (blk < 32) {
    int id = (blk - 16) * 512 + t;
    const int st = 16 * 512;
    for (int i = id; i < 32768; i += st) stats[i] = 0.0f;
    for (int i = id; i < 128 * 160; i += st) {
      int n = i / 160, k = i - n * 160;
      float v = (k < 128) ? w0[n * 131 + 3 + k] : (k < 131) ? w0[n * 131 + k - 128] : 0.0f;
      wbf0[i] = f2bf(v);
    }
    for (int i = id; i < 128 * 128; i += st) wbf1[i] = f2bf(w1[i]);
    for (int i = id; i < 256 * 128; i += st) wbf2[i] = f2bf(w2[i]);
  } else {
    float (*tile)[33] = (float(*)[33])smem;
    int blk2 = blk - 32;
    int n0 = (blk2 & 127) * 32;
    int c0 = ((blk2 >> 7) & 3) * 32;
    int b = blk2 >> 9;
    int tx = t & 31, ty = t >> 5;
    #pragma unroll
    for (int j = 0; j < 32; j += 16)
      tile[ty + j][tx] = feat[((size_t)b * 128 + c0 + ty + j) * N_ + n0 + tx];
    __syncthreads();
    #pragma unroll
    for (int j = 0; j < 32; j += 16)
      featT[((size_t)b * N_ + n0 + ty + j) * 128 + c0 + tx] = f2bf(tile[tx][ty + j]);
  }
}

// ---------------- ball query (standalone; bit-exact formula) ----------------
__global__ __launch_bounds__(256) void k_ballq(const float* __restrict__ xyz,
                                               const float* __restrict__ new_xyz,
                                               int* __restrict__ ball_idx) {
  int b = blockIdx.y;
  int s = blockIdx.x * 4 + (threadIdx.x >> 6);
  int lane = threadIdx.x & 63;
  const float* pb = xyz + (size_t)b * N_ * 3;
  size_t q = (size_t)b * S_ + s;
  float qx = new_xyz[q * 3], qy = new_xyz[q * 3 + 1], qz = new_xyz[q * 3 + 2];
  float sq = __fadd_rn(__fadd_rn(__fmul_rn(qx, qx), __fmul_rn(qy, qy)), __fmul_rn(qz, qz));
  int* out = ball_idx + q * K_;
  int total = 0;
  int first_idx = -1;
  for (int basei = 0; basei < N_; basei += 64) {
    int i = basei + lane;
    float fx = pb[i * 3], fy = pb[i * 3 + 1], fz = pb[i * 3 + 2];
    float dot = __fmul_rn(qx, fx);
    dot = __fadd_rn(dot, __fmul_rn(qy, fy));
    dot = __fadd_rn(dot, __fmul_rn(qz, fz));
    float sd = __fadd_rn(__fadd_rn(__fmul_rn(fx, fx), __fmul_rn(fy, fy)), __fmul_rn(fz, fz));
    float dist = __fadd_rn(__fadd_rn(__fmul_rn(-2.0f, dot), sq), sd);
    bool within = (dist <= 0.36f);
    u64 m = __ballot(within);
    if (first_idx < 0 && m) first_idx = basei + __ffsll((long long)m) - 1;
    if (within) {
      int pos = total + __popcll(m & ((1ull << lane) - 1ull));
      if (pos < K_) out[pos] = i;
    }
    total += (int)__popcll(m);
    if (total >= K_) break;
  }
  if (total < K_) {
    int k2 = total + lane;
    if (k2 < K_) out[k2] = first_idx;
  }
}

// ============ MFMA layer kernels — A in registers, W-only LDS (r10) ============
#define MFMA(a, b, c) __builtin_amdgcn_mfma_f32_16x16x32_bf16(a, b, c, 0, 0, 0)

// ---- layer 1: gather(reg) + matmul K=131(pad160)->128 ----
__global__ __launch_bounds__(256) void k_layer1(
    const float* __restrict__ xyz, const float* __restrict__ new_xyz,
    const unsigned short* __restrict__ featT, const int* __restrict__ ball_idx,
    const unsigned short* __restrict__ wbf0, const float* __restrict__ b0,
    unsigned short* __restrict__ y, float* __restrict__ stats) {
  __shared__ __align__(16) unsigned short Wl[128 * PITCH1];   // 42 KB, W only
  __shared__ float sbias[128];
  int bb = blockIdx.y, s0 = blockIdx.x * 4, t = threadIdx.x;
  int w = t >> 6, L = t & 63, lm = L & 15, lg = L >> 4;
  size_t qg = (size_t)bb * S_ + s0 + w;

  // A prefetch: per-lane 16B global loads (rows = this wave's 32 rows)
  int p0 = ball_idx[qg * K_ + lm];
  int p1 = ball_idx[qg * K_ + 16 + lm];
  const unsigned short* f0 = featT + ((size_t)bb * N_ + p0) * 128;
  const unsigned short* f1 = featT + ((size_t)bb * N_ + p1) * 128;
  bf16x8 a0[5], a1[5];
  #pragma unroll
  for (int kt = 0; kt < 4; ++kt) {
    a0[kt] = *(const bf16x8*)(f0 + kt * 32 + lg * 8);
    a1[kt] = *(const bf16x8*)(f1 + kt * 32 + lg * 8);
  }
  a0[4] = (bf16x8){0, 0, 0, 0, 0, 0, 0, 0};
  a1[4] = (bf16x8){0, 0, 0, 0, 0, 0, 0, 0};
  if (lg == 0) {   // xyz diff occupies k=128..130 (only lg==0 covers 128..135)
    float nx = new_xyz[qg * 3], ny = new_xyz[qg * 3 + 1], nz = new_xyz[qg * 3 + 2];
    const float* pp0 = xyz + ((size_t)bb * N_ + p0) * 3;
    const float* pp1 = xyz + ((size_t)bb * N_ + p1) * 3;
    a0[4][0] = (short)f2bf(pp0[0] - nx);
    a0[4][1] = (short)f2bf(pp0[1] - ny);
    a0[4][2] = (short)f2bf(pp0[2] - nz);
    a1[4][0] = (short)f2bf(pp1[0] - nx);
    a1[4][1] = (short)f2bf(pp1[1] - ny);
    a1[4][2] = (short)f2bf(pp1[2] - nz);
  }
  // stage W
  {
    int n = t >> 1, h = t & 1;
    const uint4* wr = (const uint4*)(wbf0 + n * 160 + h * 80);
    uint4* wl = (uint4*)(Wl + n * PITCH1 + h * 80);
    #pragma unroll
    for (int i = 0; i < 10; ++i) wl[i] = wr[i];
    if (t < 128) sbias[t] = b0[t];
  }
  __syncthreads();
  f32x4 acc[2][8];
  #pragma unroll
  for (int mi = 0; mi < 2; ++mi)
    #pragma unroll
    for (int nt = 0; nt < 8; ++nt) acc[mi][nt] = (f32x4){0.f, 0.f, 0.f, 0.f};
  #pragma unroll
  for (int kt = 0; kt < 5; ++kt) {
    int ko = kt * 32 + lg * 8;
    bf16x8 bv[8];
    #pragma unroll
    for (int nt = 0; nt < 8; ++nt)
      bv[nt] = *(const bf16x8*)&Wl[(nt * 16 + lm) * PITCH1 + ko];
    #pragma unroll
    for (int nt = 0; nt < 8; ++nt) {
      acc[0][nt] = MFMA(a0[kt], bv[nt], acc[0][nt]);
      acc[1][nt] = MFMA(a1[kt], bv[nt], acc[1][nt]);
    }
  }
  int slot = blockIdx.x & 31;
  #pragma unroll
  for (int nt = 0; nt < 8; ++nt) {
    int col = nt * 16 + lm;
    float bo = sbias[col];
    float s1 = 0.f, s2 = 0.f;
    #pragma unroll
    for (int mi = 0; mi < 2; ++mi)
      #pragma unroll
      for (int r = 0; r < 4; ++r) {
        float yv = acc[mi][nt][r] + bo;
        s1 += yv; s2 += yv * yv;
        int ks = mi * 16 + lg * 4 + r;
        y[(qg * K_ + ks) * 128 + col] = f2bf(yv);
      }
    s1 += __shfl_xor(s1, 16); s2 += __shfl_xor(s2, 16);
    s1 += __shfl_xor(s1, 32); s2 += __shfl_xor(s2, 32);
    if (lg == 0) {
      atomicAdd(stats + ((size_t)slot * 128 + col) * 2, s1);
      atomicAdd(stats + ((size_t)slot * 128 + col) * 2 + 1, s2);
    }
  }
}

// ---- layer 2: murs fold + BN+relu(reg) + matmul 128->128, y IN-PLACE ----
__global__ __launch_bounds__(256) void k_layer2(
    unsigned short* y, const float* __restrict__ stats,
    const float* __restrict__ gamma, const float* __restrict__ beta,
    const unsigned short* __restrict__ wbf1, const float* __restrict__ b1,
    float* __restrict__ stats2) {
  __shared__ __align__(16) unsigned short Wl[128 * PITCH2];   // 34 KB, W only
  __shared__ __align__(16) float sa[128], sd[128];
  __shared__ float sbias[128];
  int bb = blockIdx.y, s0 = blockIdx.x * 4, t = threadIdx.x;
  int w = t >> 6, L = t & 63, lm = L & 15, lg = L >> 4;
  size_t qg = (size_t)bb * S_ + s0 + w;

  // raw A prefetch (before barrier; BN applied after)
  const u16x8* yr0 = (const u16x8*)(y + (qg * K_ + lm) * 128);
  const u16x8* yr1 = (const u16x8*)(y + (qg * K_ + 16 + lm) * 128);
  u16x8 raw0[4], raw1[4];
  #pragma unroll
  for (int kt = 0; kt < 4; ++kt) { raw0[kt] = yr0[kt * 4 + lg]; raw1[kt] = yr1[kt * 4 + lg]; }

  // murs fold (identical arithmetic to the old k_finalize)
  if (t < 128) {
    float s1 = 0.0f, s2 = 0.0f;
    for (int sl = 0; sl < 32; ++sl) {
      s1 += stats[((size_t)sl * 128 + t) * 2];
      s2 += stats[((size_t)sl * 128 + t) * 2 + 1];
    }
    const float inv = 1.0f / 524288.0f;
    float mu = s1 * inv;
    float var = s2 * inv - mu * mu;
    float a = gamma[t] * rsqrtf(var + 1e-5f);
    sa[t] = a;
    sd[t] = beta[t] - a * mu;
    sbias[t] = b1[t];
  }
  // stage W
  {
    int n = t >> 1, h = t & 1;
    const uint4* wr = (const uint4*)(wbf1 + n * 128 + h * 64);
    uint4* wl = (uint4*)(Wl + n * PITCH2 + h * 64);
    #pragma unroll
    for (int i = 0; i < 8; ++i) wl[i] = wr[i];
  }
  __syncthreads();
  // BN+relu into A fragments (each element consumed by exactly one lane)
  bf16x8 a0[4], a1[4];
  #pragma unroll
  for (int kt = 0; kt < 4; ++kt) {
    int c = kt * 32 + lg * 8;
    f32x4 A0 = *(const f32x4*)&sa[c], A1 = *(const f32x4*)&sa[c + 4];
    f32x4 D0 = *(const f32x4*)&sd[c], D1 = *(const f32x4*)&sd[c + 4];
    #pragma unroll
    for (int j = 0; j < 4; ++j) {
      a0[kt][j]     = (short)f2bf(fmaxf(A0[j] * bf2f(raw0[kt][j])     + D0[j], 0.f));
      a0[kt][j + 4] = (short)f2bf(fmaxf(A1[j] * bf2f(raw0[kt][j + 4]) + D1[j], 0.f));
      a1[kt][j]     = (short)f2bf(fmaxf(A0[j] * bf2f(raw1[kt][j])     + D0[j], 0.f));
      a1[kt][j + 4] = (short)f2bf(fmaxf(A1[j] * bf2f(raw1[kt][j + 4]) + D1[j], 0.f));
    }
  }
  f32x4 acc[2][8];
  #pragma unroll
  for (int mi = 0; mi < 2; ++mi)
    #pragma unroll
    for (int nt = 0; nt < 8; ++nt) acc[mi][nt] = (f32x4){0.f, 0.f, 0.f, 0.f};
  #pragma unroll
  for (int kt = 0; kt < 4; ++kt) {
    int ko = kt * 32 + lg * 8;
    bf16x8 bv[8];
    #pragma unroll
    for (int nt = 0; nt < 8; ++nt)
      bv[nt] = *(const bf16x8*)&Wl[(nt * 16 + lm) * PITCH2 + ko];
    #pragma unroll
    for (int nt = 0; nt < 8; ++nt) {
      acc[0][nt] = MFMA(a0[kt], bv[nt], acc[0][nt]);
      acc[1][nt] = MFMA(a1[kt], bv[nt], acc[1][nt]);
    }
  }
  int slot = blockIdx.x & 31;
  #pragma unroll
  for (int nt = 0; nt < 8; ++nt) {
    int col = nt * 16 + lm;
    float bo = sbias[col];
    float s1 = 0.f, s2 = 0.f;
    #pragma unroll
    for (int mi = 0; mi < 2; ++mi)
      #pragma unroll
      for (int r = 0; r < 4; ++r) {
        float yv = acc[mi][nt][r] + bo;
        s1 += yv; s2 += yv * yv;
        int ks = mi * 16 + lg * 4 + r;
        y[(qg * K_ + ks) * 128 + col] = f2bf(yv);
      }
    s1 += __shfl_xor(s1, 16); s2 += __shfl_xor(s2, 16);
    s1 += __shfl_xor(s1, 32); s2 += __shfl_xor(s2, 32);
    if (lg == 0) {
      atomicAdd(stats2 + ((size_t)slot * 128 + col) * 2, s1);
      atomicAdd(stats2 + ((size_t)slot * 128 + col) * 2 + 1, s2);
    }
  }
}

// ---- layer 3: murs fold + BN+relu(reg) + matmul 128->256 (z-split) ----
__global__ __launch_bounds__(256) void k_layer3(
    const unsigned short* __restrict__ y, const float* __restrict__ stats2,
    const float* __restrict__ gamma, const float* __restrict__ beta,
    const unsigned short* __restrict__ wbf2, const float* __restrict__ b2,
    unsigned short* __restrict__ ymax, unsigned short* __restrict__ ymin,
    float* __restrict__ stats3) {
  __shared__ __align__(16) unsigned short Wl[128 * PITCH2];
  __shared__ __align__(16) float sa[128], sd[128];
  __shared__ float sbias[128];
  int bb = blockIdx.y, s0 = blockIdx.x * 4, nh = blockIdx.z, t = threadIdx.x;
  int w = t >> 6, L = t & 63, lm = L & 15, lg = L >> 4;
  size_t qg = (size_t)bb * S_ + s0 + w;

  const u16x8* yr0 = (const u16x8*)(y + (qg * K_ + lm) * 128);
  const u16x8* yr1 = (const u16x8*)(y + (qg * K_ + 16 + lm) * 128);
  u16x8 raw0[4], raw1[4];
  #pragma unroll
  for (int kt = 0; kt < 4; ++kt) { raw0[kt] = yr0[kt * 4 + lg]; raw1[kt] = yr1[kt * 4 + lg]; }

  if (t < 128) {
    float s1 = 0.0f, s2 = 0.0f;
    for (int sl = 0; sl < 32; ++sl) {
      s1 += stats2[((size_t)sl * 128 + t) * 2];
      s2 += stats2[((size_t)sl * 128 + t) * 2 + 1];
    }
    const float inv = 1.0f / 524288.0f;
    float mu = s1 * inv;
    float var = s2 * inv - mu * mu;
    float a = gamma[t] * rsqrtf(var + 1e-5f);
    sa[t] = a;
    sd[t] = beta[t] - a * mu;
    sbias[t] = b2[nh * 128 + t];
  }
  {
    int n = t >> 1, h = t & 1;
    const uint4* wr = (const uint4*)(wbf2 + (size_t)(nh * 128 + n) * 128 + h * 64);
    uint4* wl = (uint4*)(Wl + n * PITCH2 + h * 64);
    #pragma unroll
    for (int i = 0; i < 8; ++i) wl[i] = wr[i];
  }
  __syncthreads();
  bf16x8 a0[4], a1[4];
  #pragma unroll
  for (int kt = 0; kt < 4; ++kt) {
    int c = kt * 32 + lg * 8;
    f32x4 A0 = *(const f32x4*)&sa[c], A1 = *(const f32x4*)&sa[c + 4];
    f32x4 D0 = *(const f32x4*)&sd[c], D1 = *(const f32x4*)&sd[c + 4];
    #pragma unroll
    for (int j = 0; j < 4; ++j) {
      a0[kt][j]     = (short)f2bf(fmaxf(A0[j] * bf2f(raw0[kt][j])     + D0[j], 0.f));
      a0[kt][j + 4] = (short)f2bf(fmaxf(A1[j] * bf2f(raw0[kt][j + 4]) + D1[j], 0.f));
      a1[kt][j]     = (short)f2bf(fmaxf(A0[j] * bf2f(raw1[kt][j])     + D0[j], 0.f));
      a1[kt][j + 4] = (short)f2bf(fmaxf(A1[j] * bf2f(raw1[kt][j + 4]) + D1[j], 0.f));
    }
  }
  f32x4 acc[2][8];
  #pragma unroll
  for (int mi = 0; mi < 2; ++mi)
    #pragma unroll
    for (int nt = 0; nt < 8; ++nt) acc[mi][nt] = (f32x4){0.f, 0.f, 0.f, 0.f};
  #pragma unroll
  for (int kt = 0; kt < 4; ++kt) {
    int ko = kt * 32 + lg * 8;
    bf16x8 bv[8];
    #pragma unroll
    for (int nt = 0; nt < 8; ++nt)
      bv[nt] = *(const bf16x8*)&Wl[(nt * 16 + lm) * PITCH2 + ko];
    #pragma unroll
    for (int nt = 0; nt < 8; ++nt) {
      acc[0][nt] = MFMA(a0[kt], bv[nt], acc[0][nt]);
      acc[1][nt] = MFMA(a1[kt], bv[nt], acc[1][nt]);
    }
  }
  int slot = blockIdx.x & 31;
  #pragma unroll
  for (int nt = 0; nt < 8; ++nt) {
    int col = nt * 16 + lm;
    int o = nh * 128 + col;
    float bo = sbias[col];
    float s1 = 0.f, s2 = 0.f, mx = -3.4e38f, mn = 3.4e38f;
    #pragma unroll
    for (int mi = 0; mi < 2; ++mi)
      #pragma unroll
      for (int r = 0; r < 4; ++r) {
        float yv = acc[mi][nt][r] + bo;
        s1 += yv; s2 += yv * yv;
        mx = fmaxf(mx, yv); mn = fminf(mn, yv);
      }
    s1 += __shfl_xor(s1, 16); s2 += __shfl_xor(s2, 16);
    s1 += __shfl_xor(s1, 32); s2 += __shfl_xor(s2, 32);
    mx = fmaxf(mx, __shfl_xor(mx, 16)); mx = fmaxf(mx, __shfl_xor(mx, 32));
    mn = fminf(mn, __shfl_xor(mn, 16)); mn = fminf(mn, __shfl_xor(mn, 32));
    if (lg == 0) {
      ymax[qg * 256 + o] = f2bf(mx);
      ymin[qg * 256 + o] = f2bf(mn);
      atomicAdd(stats3 + ((size_t)slot * 256 + o) * 2, s1);
      atomicAdd(stats3 + ((size_t)slot * 256 + o) * 2 + 1, s2);
    }
  }
}

// -------- final: murs fold + select extreme by sign(a) + BN+relu + transpose --------
__global__ __launch_bounds__(256) void k_final(const unsigned short* __restrict__ ymax,
                                               const unsigned short* __restrict__ ymin,
                                               const float* __restrict__ stats3,
                                               const float* __restrict__ gamma,
                                               const float* __restrict__ beta,
                                               float* __restrict__ out2) {
  __shared__ float tile[32][33];
  __shared__ float smA[32], smD[32];
  int b = blockIdx.z, o0 = blockIdx.y * 32, s0 = blockIdx.x * 32;
  int tx = threadIdx.x, ty = threadIdx.y;
  if (ty == 0) {
    int c = o0 + tx;
    float s1 = 0.0f, s2 = 0.0f;
    for (int sl = 0; sl < 32; ++sl) {
      s1 += stats3[((size_t)sl * 256 + c) * 2];
      s2 += stats3[((size_t)sl * 256 + c) * 2 + 1];
    }
    const float inv = 1.0f / 524288.0f;
    float mu = s1 * inv;
    float var = s2 * inv - mu * mu;
    float a = gamma[c] * rsqrtf(var + 1e-5f);
    smA[tx] = a;
    smD[tx] = beta[c] - a * mu;
  }
  __syncthreads();
  float a_rd = smA[tx];
  #pragma unroll
  for (int j = 0; j < 32; j += 8) {
    size_t src = ((size_t)b * S_ + s0 + ty + j) * 256 + o0 + tx;
    tile[ty + j][tx] = (a_rd >= 0.0f) ? bf2f(ymax[src]) : bf2f(ymin[src]);
  }
  __syncthreads();
  #pragma unroll
  for (int j = 0; j < 32; j += 8) {
    float a = smA[ty + j], dd = smD[ty + j];
    out2[((size_t)b * 256 + o0 + ty + j) * S_ + s0 + tx] = fmaxf(a * tile[tx][ty + j] + dd, 0.0f);
  }
}

extern "C" void kernel_launch(void* const* d_in, const int* in_sizes, int n_in,
                              void* d_out, int out_size, void* d_ws, size_t ws_size,
                              hipStream_t stream) {
  (void)in_sizes; (void)n_in; (void)out_size; (void)ws_size;
  const float* xyz  = (const float*)d_in[0];
  const float* feat = (const float*)d_in[1];
  const float* w0   = (const float*)d_in[2];
  const float* b0   = (const float*)d_in[3];
  const float* ga0  = (const float*)d_in[4];
  const float* be0  = (const float*)d_in[5];
  const float* w1   = (const float*)d_in[6];
  const float* b1   = (const float*)d_in[7];
  const float* ga1  = (const float*)d_in[8];
  const float* be1  = (const float*)d_in[9];
  const float* w2   = (const float*)d_in[10];
  const float* b2   = (const float*)d_in[11];
  const float* ga2  = (const float*)d_in[12];
  const float* be2  = (const float*)d_in[13];

  float* out_xyz  = (float*)d_out;
  float* out_feat = out_xyz + (size_t)B_ * S_ * 3;

  char* ws = (char*)d_ws;
  size_t off = 0;
  auto alloc = [&](size_t bytes) -> void* {
    void* p = ws + off;
    off += (bytes + 255) & ~(size_t)255;
    return p;
  };
  unsigned short* featT = (unsigned short*)alloc((size_t)B_ * N_ * 128 * 2);  // 16.8 MB bf16
  int*   ball  = (int*)alloc((size_t)B_ * S_ * K_ * 4);                       // 2.1 MB
  float* stats = (float*)alloc(32768 * 4);
  unsigned short* wbf0 = (unsigned short*)alloc(128 * 160 * 2);
  unsigned short* wbf1 = (unsigned short*)alloc(128 * 128 * 2);
  unsigned short* wbf2 = (unsigned short*)alloc(256 * 128 * 2);
  unsigned short* ymaxb = (unsigned short*)alloc((size_t)B_ * S_ * 256 * 2);  // 8.4 MB
  unsigned short* yminb = (unsigned short*)alloc((size_t)B_ * S_ * 256 * 2);  // 8.4 MB
  unsigned short* y = (unsigned short*)alloc((size_t)B_ * S_ * K_ * 128 * 2); // 134 MB

  // blocks: 16 fps | 16 init | 8192 transpose
  k_front<<<16 + 16 + 8192, 512, 0, stream>>>(xyz, out_xyz, feat, featT,
                                              w0, w1, w2, wbf0, wbf1, wbf2, stats);
  k_ballq<<<dim3(256, 16), 256, 0, stream>>>(xyz, out_xyz, ball);
  k_layer1<<<dim3(256, 16), 256, 0, stream>>>(xyz, out_xyz, featT, ball, wbf0, b0, y, stats);
  k_layer2<<<dim3(256, 16), 256, 0, stream>>>(y, stats, ga0, be0, wbf1, b1, stats + 8192);
  k_layer3<<<dim3(256, 16, 2), 256, 0, stream>>>(y, stats + 8192, ga1, be1, wbf2, b2,
                                                 ymaxb, yminb, stats + 16384);
  k_final<<<dim3(32, 8, 16), dim3(32, 8), 0, stream>>>(ymaxb, yminb, stats + 16384,
                                                       ga2, be2, out_feat);
}

// Round 11
// 1084.291 us; speedup vs baseline: 1.3550x; 1.0451x over previous
//
#include <hip/hip_runtime.h>

#define B_ 16
#define N_ 4096
#define S_ 1024
#define K_ 32
#define PITCH2 136   // 128 + 8 shorts: b128 frag reads -> 2-way bank alias (free)
#define PITCH1 168   // 160 + 8 shorts

typedef unsigned long long u64;
typedef short bf16x8 __attribute__((ext_vector_type(8)));
typedef unsigned short u16x8 __attribute__((ext_vector_type(8)));
typedef float f32x4 __attribute__((ext_vector_type(4)));
typedef float f32x2 __attribute__((ext_vector_type(2)));

__device__ __forceinline__ unsigned short f2bf(float f) {
  unsigned u = __float_as_uint(f);
  unsigned r = (u + 0x7FFFu + ((u >> 16) & 1u)) >> 16;
  return (unsigned short)r;
}
__device__ __forceinline__ float bf2f(unsigned short h) {
  return __uint_as_float(((unsigned)h) << 16);
}

// DPP wave64 max reduce: shr1,2,4,8 + bcast15 + bcast31 -> lane 63 = wave max
#define DPP_MAX(v, ctrl)                                                        \
  {                                                                             \
    int _t = __builtin_amdgcn_update_dpp(__float_as_int(v), __float_as_int(v),  \
                                         ctrl, 0xf, 0xf, false);                \
    v = fmaxf(v, __int_as_float(_t));                                           \
  }

// ===== fused front kernel: blocks 0-15 FPS | 16-31 init | 32+ transpose =====
__global__ __launch_bounds__(512) void k_front(
    const float* __restrict__ xyz, float* __restrict__ new_xyz,
    const float* __restrict__ feat, unsigned short* __restrict__ featT,
    const float* __restrict__ w0, const float* __restrict__ w1,
    const float* __restrict__ w2, unsigned short* __restrict__ wbf0,
    unsigned short* __restrict__ wbf1, unsigned short* __restrict__ wbf2,
    float* __restrict__ stats) {
  __shared__ __align__(16) float smem[N_ * 4 + S_ + 64];
  int blk = blockIdx.x, t = threadIdx.x;

  if (blk < 16) {
#pragma clang fp contract(off)
#if __has_builtin(__builtin_amdgcn_s_setprio)
    __builtin_amdgcn_s_setprio(3);
#endif
    float4* pts = (float4*)smem;
    int* idxs = (int*)(smem + N_ * 4);
    u64* swk = (u64*)(smem + N_ * 4 + S_);
    int b = blk;
    const float* base = xyz + (size_t)b * N_ * 3;
    for (int i = t; i < N_; i += 512)
      pts[i] = make_float4(base[i * 3], base[i * 3 + 1], base[i * 3 + 2], 0.0f);
    if (t == 0) idxs[0] = 0;
    __syncthreads();
    f32x2 px[4], py[4], pz[4], pd[4];
    int i0 = t * 8;
    #pragma unroll
    for (int j = 0; j < 4; ++j) {
      float4 p0 = pts[i0 + 2 * j], p1 = pts[i0 + 2 * j + 1];
      px[j] = (f32x2){p0.x, p1.x};
      py[j] = (f32x2){p0.y, p1.y};
      pz[j] = (f32x2){p0.z, p1.z};
      pd[j] = (f32x2){1e10f, 1e10f};
    }
    int cur = 0;
    for (int it = 0; it < S_; ++it) {
      float4 c = pts[cur];
      f32x2 c2x = (f32x2){c.x, c.x}, c2y = (f32x2){c.y, c.y}, c2z = (f32x2){c.z, c.z};
      float bestv = -1.0f; int besti = 0;
      #pragma unroll
      for (int j = 0; j < 4; ++j) {
        f32x2 dx = px[j] - c2x;
        f32x2 dy = py[j] - c2y;
        f32x2 dz = pz[j] - c2z;
        f32x2 d = (dx * dx + dy * dy) + dz * dz;
        f32x2 dm = __builtin_elementwise_min(pd[j], d);
        pd[j] = dm;
        if (dm.x > bestv) { bestv = dm.x; besti = 2 * j; }
        if (dm.y > bestv) { bestv = dm.y; besti = 2 * j + 1; }
      }
      float v = bestv;
      DPP_MAX(v, 0x111);
      DPP_MAX(v, 0x112);
      DPP_MAX(v, 0x114);
      DPP_MAX(v, 0x118);
      DPP_MAX(v, 0x142);
      DPP_MAX(v, 0x143);
      float wmax = __int_as_float(__builtin_amdgcn_readlane(__float_as_int(v), 63));
      u64 mask = __ballot(bestv == wmax);
      int owner = __ffsll((long long)mask) - 1;
      int widx = __builtin_amdgcn_readlane(i0 + besti, owner);
      if ((t & 63) == 0)
        swk[(it & 1) * 8 + (t >> 6)] =
            ((u64)__float_as_uint(wmax) << 32) | (unsigned)(4095 - widx);
      __syncthreads();
      const u64* kk = swk + (it & 1) * 8;
      u64 k0 = kk[0];
      #pragma unroll
      for (int w = 1; w < 8; ++w) if (kk[w] > k0) k0 = kk[w];
      cur = 4095 - (int)(unsigned)(k0 & 0xFFFFFFFFull);
      if (t == 0 && it + 1 < S_) idxs[it + 1] = cur;
    }
    __syncthreads();
    for (int i = t; i < S_; i += 512) {
      float4 v = pts[idxs[i]];
      size_t o = ((size_t)b * S_ + i) * 3;
      new_xyz[o] = v.x; new_xyz[o + 1] = v.y; new_xyz[o + 2] = v.z;
    }
  } else if (blk < 32) {
    int id = (blk - 16) * 512 + t;
    const int st = 16 * 512;
    for (int i = id; i < 32768; i += st) stats[i] = 0.0f;
    for (int i = id; i < 128 * 160; i += st) {
      int n = i / 160, k = i - n * 160;
      float v = (k < 128) ? w0[n * 131 + 3 + k] : (k < 131) ? w0[n * 131 + k - 128] : 0.0f;
      wbf0[i] = f2bf(v);
    }
    for (int i = id; i < 128 * 128; i += st) wbf1[i] = f2bf(w1[i]);
    for (int i = id; i < 256 * 128; i += st) wbf2[i] = f2bf(w2[i]);
  } else {
    float (*tile)[33] = (float(*)[33])smem;
    int blk2 = blk - 32;
    int n0 = (blk2 & 127) * 32;
    int c0 = ((blk2 >> 7) & 3) * 32;
    int b = blk2 >> 9;
    int tx = t & 31, ty = t >> 5;
    #pragma unroll
    for (int j = 0; j < 32; j += 16)
      tile[ty + j][tx] = feat[((size_t)b * 128 + c0 + ty + j) * N_ + n0 + tx];
    __syncthreads();
    #pragma unroll
    for (int j = 0; j < 32; j += 16)
      featT[((size_t)b * N_ + n0 + ty + j) * 128 + c0 + tx] = f2bf(tile[tx][ty + j]);
  }
}

// ---------------- ball query (standalone; bit-exact formula) ----------------
__global__ __launch_bounds__(256) void k_ballq(const float* __restrict__ xyz,
                                               const float* __restrict__ new_xyz,
                                               int* __restrict__ ball_idx) {
  int b = blockIdx.y;
  int s = blockIdx.x * 4 + (threadIdx.x >> 6);
  int lane = threadIdx.x & 63;
  const float* pb = xyz + (size_t)b * N_ * 3;
  size_t q = (size_t)b * S_ + s;
  float qx = new_xyz[q * 3], qy = new_xyz[q * 3 + 1], qz = new_xyz[q * 3 + 2];
  float sq = __fadd_rn(__fadd_rn(__fmul_rn(qx, qx), __fmul_rn(qy, qy)), __fmul_rn(qz, qz));
  int* out = ball_idx + q * K_;
  int total = 0;
  int first_idx = -1;
  for (int basei = 0; basei < N_; basei += 64) {
    int i = basei + lane;
    float fx = pb[i * 3], fy = pb[i * 3 + 1], fz = pb[i * 3 + 2];
    float dot = __fmul_rn(qx, fx);
    dot = __fadd_rn(dot, __fmul_rn(qy, fy));
    dot = __fadd_rn(dot, __fmul_rn(qz, fz));
    float sd = __fadd_rn(__fadd_rn(__fmul_rn(fx, fx), __fmul_rn(fy, fy)), __fmul_rn(fz, fz));
    float dist = __fadd_rn(__fadd_rn(__fmul_rn(-2.0f, dot), sq), sd);
    bool within = (dist <= 0.36f);
    u64 m = __ballot(within);
    if (first_idx < 0 && m) first_idx = basei + __ffsll((long long)m) - 1;
    if (within) {
      int pos = total + __popcll(m & ((1ull << lane) - 1ull));
      if (pos < K_) out[pos] = i;
    }
    total += (int)__popcll(m);
    if (total >= K_) break;
  }
  if (total < K_) {
    int k2 = total + lane;
    if (k2 < K_) out[k2] = first_idx;
  }
}

// ==== MFMA layer kernels — persistent blocks: W/murs staged ONCE, then a
// barrier-free tile loop (A lives in registers since r10) ====
#define MFMA(a, b, c) __builtin_amdgcn_mfma_f32_16x16x32_bf16(a, b, c, 0, 0, 0)
#define NTILES 4096   // 16 batches x 256 s0-tiles

// ---- layer 1: gather(reg) + matmul K=131(pad160)->128 ----
__global__ __launch_bounds__(256) void k_layer1(
    const float* __restrict__ xyz, const float* __restrict__ new_xyz,
    const unsigned short* __restrict__ featT, const int* __restrict__ ball_idx,
    const unsigned short* __restrict__ wbf0, const float* __restrict__ b0,
    unsigned short* __restrict__ y, float* __restrict__ stats) {
  __shared__ __align__(16) unsigned short Wl[128 * PITCH1];   // 42 KB, W only
  __shared__ float sbias[128];
  int t = threadIdx.x;
  int w = t >> 6, L = t & 63, lm = L & 15, lg = L >> 4;
  {
    int n = t >> 1, h = t & 1;
    const uint4* wr = (const uint4*)(wbf0 + n * 160 + h * 80);
    uint4* wl = (uint4*)(Wl + n * PITCH1 + h * 80);
    #pragma unroll
    for (int i = 0; i < 10; ++i) wl[i] = wr[i];
    if (t < 128) sbias[t] = b0[t];
  }
  __syncthreads();

  for (int tile = blockIdx.x; tile < NTILES; tile += gridDim.x) {
    int bb = tile >> 8;
    int s0 = (tile & 255) * 4;
    size_t qg = (size_t)bb * S_ + s0 + w;

    int p0 = ball_idx[qg * K_ + lm];
    int p1 = ball_idx[qg * K_ + 16 + lm];
    const unsigned short* f0 = featT + ((size_t)bb * N_ + p0) * 128;
    const unsigned short* f1 = featT + ((size_t)bb * N_ + p1) * 128;
    bf16x8 a0[5], a1[5];
    #pragma unroll
    for (int kt = 0; kt < 4; ++kt) {
      a0[kt] = *(const bf16x8*)(f0 + kt * 32 + lg * 8);
      a1[kt] = *(const bf16x8*)(f1 + kt * 32 + lg * 8);
    }
    a0[4] = (bf16x8){0, 0, 0, 0, 0, 0, 0, 0};
    a1[4] = (bf16x8){0, 0, 0, 0, 0, 0, 0, 0};
    if (lg == 0) {
      float nx = new_xyz[qg * 3], ny = new_xyz[qg * 3 + 1], nz = new_xyz[qg * 3 + 2];
      const float* pp0 = xyz + ((size_t)bb * N_ + p0) * 3;
      const float* pp1 = xyz + ((size_t)bb * N_ + p1) * 3;
      a0[4][0] = (short)f2bf(pp0[0] - nx);
      a0[4][1] = (short)f2bf(pp0[1] - ny);
      a0[4][2] = (short)f2bf(pp0[2] - nz);
      a1[4][0] = (short)f2bf(pp1[0] - nx);
      a1[4][1] = (short)f2bf(pp1[1] - ny);
      a1[4][2] = (short)f2bf(pp1[2] - nz);
    }
    f32x4 acc[2][8];
    #pragma unroll
    for (int mi = 0; mi < 2; ++mi)
      #pragma unroll
      for (int nt = 0; nt < 8; ++nt) acc[mi][nt] = (f32x4){0.f, 0.f, 0.f, 0.f};
    #pragma unroll
    for (int kt = 0; kt < 5; ++kt) {
      int ko = kt * 32 + lg * 8;
      bf16x8 bv[8];
      #pragma unroll
      for (int nt = 0; nt < 8; ++nt)
        bv[nt] = *(const bf16x8*)&Wl[(nt * 16 + lm) * PITCH1 + ko];
      #pragma unroll
      for (int nt = 0; nt < 8; ++nt) {
        acc[0][nt] = MFMA(a0[kt], bv[nt], acc[0][nt]);
        acc[1][nt] = MFMA(a1[kt], bv[nt], acc[1][nt]);
      }
    }
    int slot = tile & 31;
    #pragma unroll
    for (int nt = 0; nt < 8; ++nt) {
      int col = nt * 16 + lm;
      float bo = sbias[col];
      float s1 = 0.f, s2 = 0.f;
      #pragma unroll
      for (int mi = 0; mi < 2; ++mi)
        #pragma unroll
        for (int r = 0; r < 4; ++r) {
          float yv = acc[mi][nt][r] + bo;
          s1 += yv; s2 += yv * yv;
          int ks = mi * 16 + lg * 4 + r;
          y[(qg * K_ + ks) * 128 + col] = f2bf(yv);
        }
      s1 += __shfl_xor(s1, 16); s2 += __shfl_xor(s2, 16);
      s1 += __shfl_xor(s1, 32); s2 += __shfl_xor(s2, 32);
      if (lg == 0) {
        atomicAdd(stats + ((size_t)slot * 128 + col) * 2, s1);
        atomicAdd(stats + ((size_t)slot * 128 + col) * 2 + 1, s2);
      }
    }
  }
}

// ---- layer 2: murs fold + BN+relu(reg) + matmul 128->128, y IN-PLACE ----
__global__ __launch_bounds__(256) void k_layer2(
    unsigned short* y, const float* __restrict__ stats,
    const float* __restrict__ gamma, const float* __restrict__ beta,
    const unsigned short* __restrict__ wbf1, const float* __restrict__ b1,
    float* __restrict__ stats2) {
  __shared__ __align__(16) unsigned short Wl[128 * PITCH2];   // 34 KB, W only
  __shared__ __align__(16) float sa[128], sd[128];
  __shared__ float sbias[128];
  int t = threadIdx.x;
  int w = t >> 6, L = t & 63, lm = L & 15, lg = L >> 4;
  if (t < 128) {
    float s1 = 0.0f, s2 = 0.0f;
    for (int sl = 0; sl < 32; ++sl) {
      s1 += stats[((size_t)sl * 128 + t) * 2];
      s2 += stats[((size_t)sl * 128 + t) * 2 + 1];
    }
    const float inv = 1.0f / 524288.0f;
    float mu = s1 * inv;
    float var = s2 * inv - mu * mu;
    float a = gamma[t] * rsqrtf(var + 1e-5f);
    sa[t] = a;
    sd[t] = beta[t] - a * mu;
    sbias[t] = b1[t];
  }
  {
    int n = t >> 1, h = t & 1;
    const uint4* wr = (const uint4*)(wbf1 + n * 128 + h * 64);
    uint4* wl = (uint4*)(Wl + n * PITCH2 + h * 64);
    #pragma unroll
    for (int i = 0; i < 8; ++i) wl[i] = wr[i];
  }
  __syncthreads();

  for (int tile = blockIdx.x; tile < NTILES; tile += gridDim.x) {
    int bb = tile >> 8;
    int s0 = (tile & 255) * 4;
    size_t qg = (size_t)bb * S_ + s0 + w;

    const u16x8* yr0 = (const u16x8*)(y + (qg * K_ + lm) * 128);
    const u16x8* yr1 = (const u16x8*)(y + (qg * K_ + 16 + lm) * 128);
    u16x8 raw0[4], raw1[4];
    #pragma unroll
    for (int kt = 0; kt < 4; ++kt) { raw0[kt] = yr0[kt * 4 + lg]; raw1[kt] = yr1[kt * 4 + lg]; }
    bf16x8 a0[4], a1[4];
    #pragma unroll
    for (int kt = 0; kt < 4; ++kt) {
      int c = kt * 32 + lg * 8;
      f32x4 A0 = *(const f32x4*)&sa[c], A1 = *(const f32x4*)&sa[c + 4];
      f32x4 D0 = *(const f32x4*)&sd[c], D1 = *(const f32x4*)&sd[c + 4];
      #pragma unroll
      for (int j = 0; j < 4; ++j) {
        a0[kt][j]     = (short)f2bf(fmaxf(A0[j] * bf2f(raw0[kt][j])     + D0[j], 0.f));
        a0[kt][j + 4] = (short)f2bf(fmaxf(A1[j] * bf2f(raw0[kt][j + 4]) + D1[j], 0.f));
        a1[kt][j]     = (short)f2bf(fmaxf(A0[j] * bf2f(raw1[kt][j])     + D0[j], 0.f));
        a1[kt][j + 4] = (short)f2bf(fmaxf(A1[j] * bf2f(raw1[kt][j + 4]) + D1[j], 0.f));
      }
    }
    f32x4 acc[2][8];
    #pragma unroll
    for (int mi = 0; mi < 2; ++mi)
      #pragma unroll
      for (int nt = 0; nt < 8; ++nt) acc[mi][nt] = (f32x4){0.f, 0.f, 0.f, 0.f};
    #pragma unroll
    for (int kt = 0; kt < 4; ++kt) {
      int ko = kt * 32 + lg * 8;
      bf16x8 bv[8];
      #pragma unroll
      for (int nt = 0; nt < 8; ++nt)
        bv[nt] = *(const bf16x8*)&Wl[(nt * 16 + lm) * PITCH2 + ko];
      #pragma unroll
      for (int nt = 0; nt < 8; ++nt) {
        acc[0][nt] = MFMA(a0[kt], bv[nt], acc[0][nt]);
        acc[1][nt] = MFMA(a1[kt], bv[nt], acc[1][nt]);
      }
    }
    int slot = tile & 31;
    #pragma unroll
    for (int nt = 0; nt < 8; ++nt) {
      int col = nt * 16 + lm;
      float bo = sbias[col];
      float s1 = 0.f, s2 = 0.f;
      #pragma unroll
      for (int mi = 0; mi < 2; ++mi)
        #pragma unroll
        for (int r = 0; r < 4; ++r) {
          float yv = acc[mi][nt][r] + bo;
          s1 += yv; s2 += yv * yv;
          int ks = mi * 16 + lg * 4 + r;
          y[(qg * K_ + ks) * 128 + col] = f2bf(yv);
        }
      s1 += __shfl_xor(s1, 16); s2 += __shfl_xor(s2, 16);
      s1 += __shfl_xor(s1, 32); s2 += __shfl_xor(s2, 32);
      if (lg == 0) {
        atomicAdd(stats2 + ((size_t)slot * 128 + col) * 2, s1);
        atomicAdd(stats2 + ((size_t)slot * 128 + col) * 2 + 1, s2);
      }
    }
  }
}

// ---- layer 3: murs fold + BN+relu(reg) + matmul 128->256 (nh per block.y) ----
__global__ __launch_bounds__(256) void k_layer3(
    const unsigned short* __restrict__ y, const float* __restrict__ stats2,
    const float* __restrict__ gamma, const float* __restrict__ beta,
    const unsigned short* __restrict__ wbf2, const float* __restrict__ b2,
    unsigned short* __restrict__ ymax, unsigned short* __restrict__ ymin,
    float* __restrict__ stats3) {
  __shared__ __align__(16) unsigned short Wl[128 * PITCH2];
  __shared__ __align__(16) float sa[128], sd[128];
  __shared__ float sbias[128];
  int nh = blockIdx.y, t = threadIdx.x;
  int w = t >> 6, L = t & 63, lm = L & 15, lg = L >> 4;
  if (t < 128) {
    float s1 = 0.0f, s2 = 0.0f;
    for (int sl = 0; sl < 32; ++sl) {
      s1 += stats2[((size_t)sl * 128 + t) * 2];
      s2 += stats2[((size_t)sl * 128 + t) * 2 + 1];
    }
    const float inv = 1.0f / 524288.0f;
    float mu = s1 * inv;
    float var = s2 * inv - mu * mu;
    float a = gamma[t] * rsqrtf(var + 1e-5f);
    sa[t] = a;
    sd[t] = beta[t] - a * mu;
    sbias[t] = b2[nh * 128 + t];
  }
  {
    int n = t >> 1, h = t & 1;
    const uint4* wr = (const uint4*)(wbf2 + (size_t)(nh * 128 + n) * 128 + h * 64);
    uint4* wl = (uint4*)(Wl + n * PITCH2 + h * 64);
    #pragma unroll
    for (int i = 0; i < 8; ++i) wl[i] = wr[i];
  }
  __syncthreads();

  for (int tile = blockIdx.x; tile < NTILES; tile += gridDim.x) {
    int bb = tile >> 8;
    int s0 = (tile & 255) * 4;
    size_t qg = (size_t)bb * S_ + s0 + w;

    const u16x8* yr0 = (const u16x8*)(y + (qg * K_ + lm) * 128);
    const u16x8* yr1 = (const u16x8*)(y + (qg * K_ + 16 + lm) * 128);
    u16x8 raw0[4], raw1[4];
    #pragma unroll
    for (int kt = 0; kt < 4; ++kt) { raw0[kt] = yr0[kt * 4 + lg]; raw1[kt] = yr1[kt * 4 + lg]; }
    bf16x8 a0[4], a1[4];
    #pragma unroll
    for (int kt = 0; kt < 4; ++kt) {
      int c = kt * 32 + lg * 8;
      f32x4 A0 = *(const f32x4*)&sa[c], A1 = *(const f32x4*)&sa[c + 4];
      f32x4 D0 = *(const f32x4*)&sd[c], D1 = *(const f32x4*)&sd[c + 4];
      #pragma unroll
      for (int j = 0; j < 4; ++j) {
        a0[kt][j]     = (short)f2bf(fmaxf(A0[j] * bf2f(raw0[kt][j])     + D0[j], 0.f));
        a0[kt][j + 4] = (short)f2bf(fmaxf(A1[j] * bf2f(raw0[kt][j + 4]) + D1[j], 0.f));
        a1[kt][j]     = (short)f2bf(fmaxf(A0[j] * bf2f(raw1[kt][j])     + D0[j], 0.f));
        a1[kt][j + 4] = (short)f2bf(fmaxf(A1[j] * bf2f(raw1[kt][j + 4]) + D1[j], 0.f));
      }
    }
    f32x4 acc[2][8];
    #pragma unroll
    for (int mi = 0; mi < 2; ++mi)
      #pragma unroll
      for (int nt = 0; nt < 8; ++nt) acc[mi][nt] = (f32x4){0.f, 0.f, 0.f, 0.f};
    #pragma unroll
    for (int kt = 0; kt < 4; ++kt) {
      int ko = kt * 32 + lg * 8;
      bf16x8 bv[8];
      #pragma unroll
      for (int nt = 0; nt < 8; ++nt)
        bv[nt] = *(const bf16x8*)&Wl[(nt * 16 + lm) * PITCH2 + ko];
      #pragma unroll
      for (int nt = 0; nt < 8; ++nt) {
        acc[0][nt] = MFMA(a0[kt], bv[nt], acc[0][nt]);
        acc[1][nt] = MFMA(a1[kt], bv[nt], acc[1][nt]);
      }
    }
    int slot = tile & 31;
    #pragma unroll
    for (int nt = 0; nt < 8; ++nt) {
      int col = nt * 16 + lm;
      int o = nh * 128 + col;
      float bo = sbias[col];
      float s1 = 0.f, s2 = 0.f, mx = -3.4e38f, mn = 3.4e38f;
      #pragma unroll
      for (int mi = 0; mi < 2; ++mi)
        #pragma unroll
        for (int r = 0; r < 4; ++r) {
          float yv = acc[mi][nt][r] + bo;
          s1 += yv; s2 += yv * yv;
          mx = fmaxf(mx, yv); mn = fminf(mn, yv);
        }
      s1 += __shfl_xor(s1, 16); s2 += __shfl_xor(s2, 16);
      s1 += __shfl_xor(s1, 32); s2 += __shfl_xor(s2, 32);
      mx = fmaxf(mx, __shfl_xor(mx, 16)); mx = fmaxf(mx, __shfl_xor(mx, 32));
      mn = fminf(mn, __shfl_xor(mn, 16)); mn = fminf(mn, __shfl_xor(mn, 32));
      if (lg == 0) {
        ymax[qg * 256 + o] = f2bf(mx);
        ymin[qg * 256 + o] = f2bf(mn);
        atomicAdd(stats3 + ((size_t)slot * 256 + o) * 2, s1);
        atomicAdd(stats3 + ((size_t)slot * 256 + o) * 2 + 1, s2);
      }
    }
  }
}

// -------- final: murs fold + select extreme by sign(a) + BN+relu + transpose --------
__global__ __launch_bounds__(256) void k_final(const unsigned short* __restrict__ ymax,
                                               const unsigned short* __restrict__ ymin,
                                               const float* __restrict__ stats3,
                                               const float* __restrict__ gamma,
                                               const float* __restrict__ beta,
                                               float* __restrict__ out2) {
  __shared__ float tile[32][33];
  __shared__ float smA[32], smD[32];
  int b = blockIdx.z, o0 = blockIdx.y * 32, s0 = blockIdx.x * 32;
  int tx = threadIdx.x, ty = threadIdx.y;
  if (ty == 0) {
    int c = o0 + tx;
    float s1 = 0.0f, s2 = 0.0f;
    for (int sl = 0; sl < 32; ++sl) {
      s1 += stats3[((size_t)sl * 256 + c) * 2];
      s2 += stats3[((size_t)sl * 256 + c) * 2 + 1];
    }
    const float inv = 1.0f / 524288.0f;
    float mu = s1 * inv;
    float var = s2 * inv - mu * mu;
    float a = gamma[c] * rsqrtf(var + 1e-5f);
    smA[tx] = a;
    smD[tx] = beta[c] - a * mu;
  }
  __syncthreads();
  float a_rd = smA[tx];
  #pragma unroll
  for (int j = 0; j < 32; j += 8) {
    size_t src = ((size_t)b * S_ + s0 + ty + j) * 256 + o0 + tx;
    tile[ty + j][tx] = (a_rd >= 0.0f) ? bf2f(ymax[src]) : bf2f(ymin[src]);
  }
  __syncthreads();
  #pragma unroll
  for (int j = 0; j < 32; j += 8) {
    float a = smA[ty + j], dd = smD[ty + j];
    out2[((size_t)b * 256 + o0 + ty + j) * S_ + s0 + tx] = fmaxf(a * tile[tx][ty + j] + dd, 0.0f);
  }
}

extern "C" void kernel_launch(void* const* d_in, const int* in_sizes, int n_in,
                              void* d_out, int out_size, void* d_ws, size_t ws_size,
                              hipStream_t stream) {
  (void)in_sizes; (void)n_in; (void)out_size; (void)ws_size;
  const float* xyz  = (const float*)d_in[0];
  const float* feat = (const float*)d_in[1];
  const float* w0   = (const float*)d_in[2];
  const float* b0   = (const float*)d_in[3];
  const float* ga0  = (const float*)d_in[4];
  const float* be0  = (const float*)d_in[5];
  const float* w1   = (const float*)d_in[6];
  const float* b1   = (const float*)d_in[7];
  const float* ga1  = (const float*)d_in[8];
  const float* be1  = (const float*)d_in[9];
  const float* w2   = (const float*)d_in[10];
  const float* b2   = (const float*)d_in[11];
  const float* ga2  = (const float*)d_in[12];
  const float* be2  = (const float*)d_in[13];

  float* out_xyz  = (float*)d_out;
  float* out_feat = out_xyz + (size_t)B_ * S_ * 3;

  char* ws = (char*)d_ws;
  size_t off = 0;
  auto alloc = [&](size_t bytes) -> void* {
    void* p = ws + off;
    off += (bytes + 255) & ~(size_t)255;
    return p;
  };
  unsigned short* featT = (unsigned short*)alloc((size_t)B_ * N_ * 128 * 2);  // 16.8 MB bf16
  int*   ball  = (int*)alloc((size_t)B_ * S_ * K_ * 4);                       // 2.1 MB
  float* stats = (float*)alloc(32768 * 4);
  unsigned short* wbf0 = (unsigned short*)alloc(128 * 160 * 2);
  unsigned short* wbf1 = (unsigned short*)alloc(128 * 128 * 2);
  unsigned short* wbf2 = (unsigned short*)alloc(256 * 128 * 2);
  unsigned short* ymaxb = (unsigned short*)alloc((size_t)B_ * S_ * 256 * 2);  // 8.4 MB
  unsigned short* yminb = (unsigned short*)alloc((size_t)B_ * S_ * 256 * 2);  // 8.4 MB
  unsigned short* y = (unsigned short*)alloc((size_t)B_ * S_ * K_ * 128 * 2); // 134 MB

  // blocks: 16 fps | 16 init | 8192 transpose
  k_front<<<16 + 16 + 8192, 512, 0, stream>>>(xyz, out_xyz, feat, featT,
                                              w0, w1, w2, wbf0, wbf1, wbf2, stats);
  k_ballq<<<dim3(256, 16), 256, 0, stream>>>(xyz, out_xyz, ball);
  // persistent grids: layer1 3 blocks/CU (43KB LDS), layer2 4/CU, layer3 (512,2)
  k_layer1<<<768, 256, 0, stream>>>(xyz, out_xyz, featT, ball, wbf0, b0, y, stats);
  k_layer2<<<1024, 256, 0, stream>>>(y, stats, ga0, be0, wbf1, b1, stats + 8192);
  k_layer3<<<dim3(512, 2), 256, 0, stream>>>(y, stats + 8192, ga1, be1, wbf2, b2,
                                             ymaxb, yminb, stats + 16384);
  k_final<<<dim3(32, 8, 16), dim3(32, 8), 0, stream>>>(ymaxb, yminb, stats + 16384,
                                                       ga2, be2, out_feat);
}